// Round 14
// baseline (641.428 us; speedup 1.0000x reference)
//
#include <hip/hip_runtime.h>
#include <hip/hip_bf16.h>
#include <math.h>

namespace {

constexpr int Bb = 8, Ll = 1024, Dd = 768, Hh = 12, DHh = 64;
constexpr int DDm = Dd * Dd;
constexpr float MAXN = 1.0f - 1e-5f;
constexpr float EPSf = 1e-15f;

typedef __attribute__((ext_vector_type(8))) short short8;
typedef __attribute__((ext_vector_type(4))) short short4v;
typedef __attribute__((ext_vector_type(4))) float f32x4;

__device__ __forceinline__ float wred64(float v) {
#pragma unroll
  for (int m = 32; m >= 1; m >>= 1) v += __shfl_xor(v, m, 64);
  return v;
}

__device__ __forceinline__ float artanh_(float x) {
  return 0.5f * logf((1.0f + x) / (1.0f - x));
}

__device__ __forceinline__ void bsplit(float x, unsigned short& h,
                                       unsigned short& l) {
  __hip_bfloat16 hb = __float2bfloat16(x);
  const float hf = __bfloat162float(hb);
  __hip_bfloat16 lb = __float2bfloat16(x - hf);
  h = *(unsigned short*)&hb;
  l = *(unsigned short*)&lb;
}

__device__ __forceinline__ unsigned short bhi(float x) {
  __hip_bfloat16 hb = __float2bfloat16(x);
  return *(unsigned short*)&hb;
}

__device__ __forceinline__ float bf2f(unsigned short u) {
  union { unsigned int i; float f; } cv;
  cv.i = ((unsigned int)u) << 16;
  return cv.f;
}

// Async global->LDS 16B DMA (gfx950). LDS dest must be wave-uniform base +
// lane*16 (linear in lane order) — swizzling is done on the SOURCE address.
__device__ __forceinline__ void gll16(const unsigned short* g,
                                      unsigned short* l) {
  __builtin_amdgcn_global_load_lds(
      (const __attribute__((address_space(1))) void*)g,
      (__attribute__((address_space(3))) void*)l, 16, 0, 0);
}

// ---------------------------------------------------------------------------
// x -> bf16 (hi only, for GEMM A) + per-row squared norm.
// ---------------------------------------------------------------------------
__global__ __launch_bounds__(768) void k_cvtx(const float* __restrict__ x,
                                              unsigned short* __restrict__ hi,
                                              float* __restrict__ xn2a) {
  const int t = threadIdx.x;
  const int row = blockIdx.x;
  const int w = t >> 6, lane = t & 63;
  __shared__ float red[12];
  const float xe = x[(size_t)row * Dd + t];
  hi[(size_t)row * Dd + t] = bhi(xe);
  const float s = wred64(xe * xe);
  if (lane == 0) red[w] = s;
  __syncthreads();
  if (t == 0) {
    float tot = 0.0f;
#pragma unroll
    for (int i = 0; i < 12; i++) tot += red[i];
    xn2a[row] = tot;
  }
}

// 4 weight matrices -> bf16 hi in one launch (blockIdx.z selects source).
__global__ __launch_bounds__(256) void k_cvt4(
    const float* __restrict__ w0, const float* __restrict__ w1,
    const float* __restrict__ w2, const float* __restrict__ w3,
    unsigned short* __restrict__ hi) {
  const int z = blockIdx.z;
  const float* in = (z == 0) ? w0 : (z == 1) ? w1 : (z == 2) ? w2 : w3;
  const int i = blockIdx.x * 256 + threadIdx.x;
  if (i >= DDm / 4) return;
  float4 v = ((const float4*)in)[i];
  ((ushort4*)(hi + (size_t)z * DDm))[i] =
      make_ushort4(bhi(v.x), bhi(v.y), bhi(v.z), bhi(v.w));
}

// ---------------------------------------------------------------------------
// Pure-bf16 MFMA GEMM: C = A @ W^T. m97-shape: 4 global_load_lds (16B DMA,
// source-side swizzle) + 8 ds_read_b128 + 16 MFMA per K-step. 16 KB LDS.
// ---------------------------------------------------------------------------
__global__ __launch_bounds__(256) void k_gemm_bf16h(
    const unsigned short* __restrict__ Ahi,
    const unsigned short* __restrict__ Whi, float* __restrict__ C) {
  constexpr int K = Dd, N = Dd;
  const int z = blockIdx.z;
  const unsigned short* Bh = Whi + (size_t)z * DDm;
  float* Cz = C + (size_t)z * 8192 * N;
  __shared__ __align__(16) unsigned short sAh[128 * 32];
  __shared__ __align__(16) unsigned short sBh[128 * 32];
  const int t = threadIdx.x;
  const int l = t & 63, wid = t >> 6;
  const int wr = wid >> 1, wc = wid & 1;
  const int m0 = blockIdx.y * 128, n0 = blockIdx.x * 128;

  const int r0 = t >> 2;
  const int kfs = ((t & 3) ^ ((r0 >> 1) & 3)) << 3;
  const size_t ga0 = (size_t)(m0 + r0) * K + kfs;
  const size_t ga1 = (size_t)(m0 + r0 + 64) * K + kfs;
  const size_t gb0 = (size_t)(n0 + r0) * K + kfs;
  const size_t gb1 = (size_t)(n0 + r0 + 64) * K + kfs;
  unsigned short* dA0 = &sAh[t * 8];
  unsigned short* dA1 = &sAh[(t + 256) * 8];
  unsigned short* dB0 = &sBh[t * 8];
  unsigned short* dB1 = &sBh[(t + 256) * 8];

  const int lar = l & 15, lkf = l >> 4;

  f32x4 acc[4][4] = {};

  for (int k0 = 0; k0 < K; k0 += 32) {
    __syncthreads();  // prior iteration's LDS reads complete
    gll16(&Ahi[ga0 + k0], dA0);
    gll16(&Ahi[ga1 + k0], dA1);
    gll16(&Bh[gb0 + k0], dB0);
    gll16(&Bh[gb1 + k0], dB1);
    __syncthreads();  // vmcnt drained -> staging visible

    short8 ah[4], bh[4];
#pragma unroll
    for (int f = 0; f < 4; f++) {
      const int ra = wr * 64 + f * 16 + lar;
      const int ia = ra * 32 + ((lkf ^ ((ra >> 1) & 3)) << 3);
      ah[f] = *(const short8*)&sAh[ia];
      const int rb = wc * 64 + f * 16 + lar;
      const int ib = rb * 32 + ((lkf ^ ((rb >> 1) & 3)) << 3);
      bh[f] = *(const short8*)&sBh[ib];
    }
#pragma unroll
    for (int i = 0; i < 4; i++)
#pragma unroll
      for (int j = 0; j < 4; j++)
        acc[i][j] = __builtin_amdgcn_mfma_f32_16x16x32_bf16(ah[i], bh[j],
                                                            acc[i][j], 0, 0, 0);
  }

#pragma unroll
  for (int i = 0; i < 4; i++)
#pragma unroll
    for (int j = 0; j < 4; j++) {
      const int row = m0 + wr * 64 + i * 16 + (l >> 4) * 4;
      const int col = n0 + wc * 64 + j * 16 + (l & 15);
      const f32x4 v = acc[i][j];
#pragma unroll
      for (int q = 0; q < 4; q++) Cz[(size_t)(row + q) * N + col] = v[q];
    }
}

// ---------------------------------------------------------------------------
// Per-row transform, one (row, mi) per block. Emits q/k/(lam*v) as bf16
// hi/lo + per-head stats.
// ---------------------------------------------------------------------------
__global__ __launch_bounds__(768) void k_qkvt3(
    const float* __restrict__ xn2a,
    const float* __restrict__ mq, const float* __restrict__ mk,
    const float* __restrict__ mv,
    unsigned short* __restrict__ qhh, unsigned short* __restrict__ qhl,
    unsigned short* __restrict__ khh, unsigned short* __restrict__ khl,
    unsigned short* __restrict__ vhh, unsigned short* __restrict__ vhl_,
    float* __restrict__ q2n, float* __restrict__ k2n,
    float* __restrict__ lam1, float beta_ratio) {
  const int t = threadIdx.x;
  const int row = blockIdx.x;  // b*L + l
  const int mi = blockIdx.y;
  const int b = row >> 10, l = row & 1023;
  const int w = t >> 6, lane = t & 63;
  __shared__ float red[12];

  const float* m = (mi == 0) ? mq : (mi == 1) ? mk : mv;
  const float me = m[(size_t)row * Dd + t];
  const float s2 = wred64(me * me);
  if (lane == 0) red[w] = s2;
  __syncthreads();
  float mn2 = 0.0f;
#pragma unroll
  for (int i = 0; i < 12; i++) mn2 += red[i];

  const float xn = sqrtf(fmaxf(xn2a[row], EPSf * EPSf));
  const float arx = artanh_(fminf(xn, MAXN));

  const float mxn = sqrtf(fmaxf(mn2, EPSf * EPSf));
  const float pn = tanhf(mxn / xn * arx);
  const float c1 = pn / mxn * fminf(1.0f, MAXN / fmaxf(pn, EPSf));
  const float nn = fmaxf(fminf(pn, MAXN), EPSf);
  const float c2 = artanh_(nn) / nn;
  const float ve = c2 * c1 * me * beta_ratio;
  const float hs = wred64(ve * ve);
  const float hn = sqrtf(fmaxf(hs, EPSf * EPSf));
  const float th = tanhf(hn);
  const float oe = th / hn * ve;
  const size_t hidx = (size_t)(b * Hh + w) * Ll + l;
  const size_t oidx = hidx * DHh + lane;
  unsigned short hu, lu;
  if (mi == 0) {
    bsplit(oe, hu, lu);
    qhh[oidx] = hu; qhl[oidx] = lu;
    if (lane == 0) q2n[hidx] = th * th;
  } else if (mi == 1) {
    bsplit(oe, hu, lu);
    khh[oidx] = hu; khl[oidx] = lu;
    if (lane == 0) k2n[hidx] = th * th;
  } else {
    const float lam = 2.0f / fmaxf(1.0f - th * th, EPSf);
    bsplit(lam * oe, hu, lu);
    vhh[oidx] = hu; vhl_[oidx] = lu;
    if (lane == 0) lam1[hidx] = lam - 1.0f;
  }
}

// ---------------------------------------------------------------------------
// Transpose lam*v per head: [k][d] -> [d][k] (bf16 hi/lo).
// ---------------------------------------------------------------------------
__global__ __launch_bounds__(256) void k_vt(const unsigned short* __restrict__ vh,
                                            const unsigned short* __restrict__ vl,
                                            unsigned short* __restrict__ th,
                                            unsigned short* __restrict__ tl) {
  __shared__ __align__(16) unsigned short sh[64 * 72];
  __shared__ __align__(16) unsigned short sl[64 * 72];
  const int t = threadIdx.x;
  const int bh = blockIdx.y, c = blockIdx.x;
  const size_t ibase = ((size_t)bh * Ll + c * 64) * DHh;
#pragma unroll
  for (int u = 0; u < 2; u++) {
    const int ch = t + u * 256, r = ch >> 3, f = ch & 7;
    *(short8*)&sh[r * 72 + f * 8] = *(const short8*)&vh[ibase + r * DHh + f * 8];
    *(short8*)&sl[r * 72 + f * 8] = *(const short8*)&vl[ibase + r * DHh + f * 8];
  }
  __syncthreads();
#pragma unroll
  for (int u = 0; u < 2; u++) {
    const int ch = t + u * 256, d = ch >> 3, kb = ch & 7;
    short8 oh, ol;
#pragma unroll
    for (int i = 0; i < 8; i++) {
      oh[i] = (short)sh[(kb * 8 + i) * 72 + d];
      ol[i] = (short)sl[(kb * 8 + i) * 72 + d];
    }
    const size_t ob = ((size_t)bh * DHh + d) * Ll + c * 64 + kb * 8;
    *(short8*)&th[ob] = oh;
    *(short8*)&tl[ob] = ol;
  }
}

// ---------------------------------------------------------------------------
// Fused attention + normalization, SINGLE kernel. Main loop (round-7
// structure) writes bf16(e) into the SECOND half of each fp32 attn row
// (coalesced); fused epilogue normalizes+expands in place (k_norm deleted).
// In-place safety: reads at step m touch bytes [2048+32m,+32); all writes
// issued so far end at 64m <= 2048+32m for m<=63 — no overlap; waves own
// disjoint rows and are lockstep.
// ---------------------------------------------------------------------------
__global__ __launch_bounds__(256) void k_attn1(
    const unsigned short* __restrict__ qhh, const unsigned short* __restrict__ qhl,
    const unsigned short* __restrict__ khh, const unsigned short* __restrict__ khl,
    const unsigned short* __restrict__ vth, const unsigned short* __restrict__ vtl,
    const float* __restrict__ q2n, const float* __restrict__ k2n,
    const float* __restrict__ lam1, const float* __restrict__ scale_p,
    float* __restrict__ attn, float* __restrict__ yh) {
  __shared__ __align__(16) unsigned short kldsh[32 * 72];
  __shared__ __align__(16) unsigned short kldsl[32 * 72];
  __shared__ __align__(16) unsigned short vldsh[64 * 36];
  __shared__ __align__(16) unsigned short vldsl[64 * 36];
  __shared__ __align__(16) unsigned short wlds[4][16 * 36];
  __shared__ __align__(16) float k2s[32];
  __shared__ __align__(16) float l1s[32];
  __shared__ __align__(16) float ik2s[32];
  __shared__ float dred[4][16];
  __shared__ float rsum_s[4][16];
  const int t = threadIdx.x, l = t & 63, w = t >> 6;
  const int lr = l & 15, lg = l >> 4;
  const int bh = blockIdx.y, q0 = blockIdx.x * 64;
  const size_t hbase = (size_t)bh * Ll;
  const float scale = scale_p[0];
  const bool sone = (scale == 1.0f);

  short8 aqh[2], aql[2];
#pragma unroll
  for (int s = 0; s < 2; s++) {
    const size_t off = (hbase + q0 + w * 16 + lr) * (size_t)DHh + s * 32 + lg * 8;
    aqh[s] = *(const short8*)&qhh[off];
    aql[s] = *(const short8*)&qhl[off];
  }
  const float q2v = q2n[hbase + q0 + w * 16 + lr];

  const int kr = t >> 3, kf = t & 7;
  const int vd = t >> 2, vf = t & 3;

  float rs = 0.0f, dacc = 0.0f;
  f32x4 pv[4] = {};

  short8 pkh, pkl, pvh, pvl;
  float k2r = 0.0f, l1r = 0.0f;
  auto load_chunk = [&](int c) {
    const size_t kg = (hbase + c * 32 + kr) * (size_t)DHh + kf * 8;
    pkh = *(const short8*)&khh[kg];
    pkl = *(const short8*)&khl[kg];
    const size_t vg = ((size_t)bh * DHh + vd) * (size_t)Ll + c * 32 + vf * 8;
    pvh = *(const short8*)&vth[vg];
    pvl = *(const short8*)&vtl[vg];
    if (t < 32) {
      k2r = k2n[hbase + c * 32 + t];
      l1r = lam1[hbase + c * 32 + t];
    }
  };
  load_chunk(0);

  for (int c = 0; c < 32; c++) {
    __syncthreads();  // prior iteration's LDS reads complete
    *(short8*)&kldsh[kr * 72 + kf * 8] = pkh;
    *(short8*)&kldsl[kr * 72 + kf * 8] = pkl;
    *(short8*)&vldsh[vd * 36 + vf * 8] = pvh;
    *(short8*)&vldsl[vd * 36 + vf * 8] = pvl;
    if (t < 32) {
      k2s[t] = k2r;
      l1s[t] = l1r;
      ik2s[t] = __builtin_amdgcn_rcpf(1.0f - k2r);
    }
    __syncthreads();  // staging visible
    if (c + 1 < 32) load_chunk(c + 1);  // prefetch hides under compute

#pragma unroll
    for (int j = 0; j < 2; j++) {
      f32x4 acc = {};
#pragma unroll
      for (int s = 0; s < 2; s++) {
        const int ko = (j * 16 + lr) * 72 + s * 32 + lg * 8;
        const short8 kfh = *(const short8*)&kldsh[ko];
        const short8 kfl = *(const short8*)&kldsl[ko];
        acc = __builtin_amdgcn_mfma_f32_16x16x32_bf16(kfh, aqh[s], acc, 0, 0, 0);
        acc = __builtin_amdgcn_mfma_f32_16x16x32_bf16(kfh, aql[s], acc, 0, 0, 0);
        acc = __builtin_amdgcn_mfma_f32_16x16x32_bf16(kfl, aqh[s], acc, 0, 0, 0);
      }
      const float4 k2q = *(const float4*)&k2s[j * 16 + lg * 4];
      const float4 l1q = *(const float4*)&l1s[j * 16 + lg * 4];
      const float4 ikq = *(const float4*)&ik2s[j * 16 + lg * 4];
      const float kq[4] = {k2q.x, k2q.y, k2q.z, k2q.w};
      const float lq[4] = {l1q.x, l1q.y, l1q.z, l1q.w};
      const float iq[4] = {ikq.x, ikq.y, ikq.z, ikq.w};
      short4v wv;
#pragma unroll
      for (int r = 0; r < 4; r++) {
        const float qk2 = acc[r] + acc[r];
        const float d = fmaxf(q2v + kq[r] - qk2, 0.0f);
        const float dn = fmaf(q2v, kq[r], 1.0f) - qk2;  // > 0.5 here
        const float m_ = fmaxf(d * dn, 1e-30f);
        const float s_ = m_ * __builtin_amdgcn_rsqf(m_);  // sqrt(d*dn)
        float e = (dn + d - s_ - s_) * iq[r];  // p*(1-q2) >= 0
        if (!sone) e = expf(scale * logf(fmaxf(e, 1e-30f)));
        rs += e;
        __hip_bfloat16 eb = __float2bfloat16(e);
        wv[r] = *(short*)&eb;
        dacc += __bfloat162float(eb) * lq[r];  // den from SAME rounded w
      }
      *(short4v*)&wlds[w][lr * 36 + j * 16 + lg * 4] = wv;
    }
    // PV: A = w (16q x 32k, bf16, wave-local), B = (lam v)^T [d][k].
    {
      const short8 wa = *(const short8*)&wlds[w][lr * 36 + lg * 8];
#pragma unroll
      for (int n = 0; n < 4; n++) {
        const int bo = (n * 16 + lr) * 36 + lg * 8;
        const short8 vbh8 = *(const short8*)&vldsh[bo];
        const short8 vbl8 = *(const short8*)&vldsl[bo];
        pv[n] = __builtin_amdgcn_mfma_f32_16x16x32_bf16(wa, vbh8, pv[n], 0, 0, 0);
        pv[n] = __builtin_amdgcn_mfma_f32_16x16x32_bf16(wa, vbl8, pv[n], 0, 0, 0);
      }
    }
    // Coalesced bf16-e store into the SECOND half of the fp32 row.
    {
      const int qy = l >> 2, cg = l & 3;
      const short8 ev = *(const short8*)&wlds[w][qy * 36 + cg * 8];
      unsigned short* eb =
          (unsigned short*)(attn + (hbase + q0 + w * 16 + qy) * (size_t)Ll);
      *(short8*)&eb[1024 + c * 32 + cg * 8] = ev;
    }
  }

  rs += __shfl_xor(rs, 16, 64);
  rs += __shfl_xor(rs, 32, 64);
  dacc += __shfl_xor(dacc, 16, 64);
  dacc += __shfl_xor(dacc, 32, 64);
  if (lg == 0) {
    rsum_s[w][lr] = rs;
    dred[w][lr] = dacc;
  }
  __syncthreads();  // bf16-e stores drained + LDS reductions visible

  // ---- Fused normalize + expand (replaces k_norm) ----
  {
    const int er = l >> 2, ec = l & 3;  // 4 lanes per row, lockstep wave
    const float rinv = 1.0f / rsum_s[w][er];
    float* prow = attn + (hbase + q0 + w * 16 + er) * (size_t)Ll;
    const unsigned short* ebase = (const unsigned short*)prow + 1024;
    for (int i = ec; i < 256; i += 4) {
      const ushort4 u4 = *(const ushort4*)&ebase[i * 4];
      float4 v;
      v.x = bf2f(u4.x) * rinv;
      v.y = bf2f(u4.y) * rinv;
      v.z = bf2f(u4.z) * rinv;
      v.w = bf2f(u4.w) * rinv;
      *(float4*)&prow[i * 4] = v;
    }
  }

  // ---- Mobius midpoint epilogue -> yh ----
  const int b = bh / Hh, h = bh % Hh;
#pragma unroll
  for (int r = 0; r < 4; r++) {
    float den = dred[w][lg * 4 + r];
    if (fabsf(den) < 1e-10f) den = 1e-10f;
    const float dinv = 1.0f / den;
    float tm[4];
    float n2 = 0.0f;
#pragma unroll
    for (int n = 0; n < 4; n++) {
      tm[n] = pv[n][r] * dinv;
      n2 += tm[n] * tm[n];
    }
    n2 += __shfl_xor(n2, 1, 64);
    n2 += __shfl_xor(n2, 2, 64);
    n2 += __shfl_xor(n2, 4, 64);
    n2 += __shfl_xor(n2, 8, 64);
    const float nn = sqrtf(fmaxf(n2, EPSf * EPSf));
    const float nc = fminf(nn, MAXN);
    const float pn = nc / (1.0f + sqrtf(fmaxf(1.0f - nc * nc, 0.0f)));
    const float f = pn / nn * fminf(1.0f, MAXN / fmaxf(pn, EPSf));
    const int ql = q0 + w * 16 + lg * 4 + r;
#pragma unroll
    for (int n = 0; n < 4; n++)
      yh[(((size_t)(b * Ll + ql)) * Hh + h) * DHh + n * 16 + lr] = f * tm[n];
  }
}

// ---------------------------------------------------------------------------
// beta_concat: per-head logmap0 / BETA_RATIO, then expmap0 over full D.
// Also emits the bf16 (hi-only) copy of yc for the projection GEMM.
// ---------------------------------------------------------------------------
__global__ __launch_bounds__(768) void k_concat(
    const float* __restrict__ yh, float* __restrict__ yc,
    unsigned short* __restrict__ ychi, float beta_ratio) {
  const int t = threadIdx.x;
  const int row = blockIdx.x;
  const int w = t >> 6, lane = t & 63;
  __shared__ float red[12];
  const float ye = yh[(size_t)row * Dd + t];
  const float hs = wred64(ye * ye);
  const float hn = sqrtf(fmaxf(hs, EPSf * EPSf));
  const float cc = artanh_(fminf(hn, MAXN)) / hn / beta_ratio;
  const float ve = cc * ye;
  const float s = wred64(ve * ve);
  if (lane == 0) red[w] = s;
  __syncthreads();
  float n2 = 0.0f;
#pragma unroll
  for (int i = 0; i < 12; i++) n2 += red[i];
  const float n = sqrtf(fmaxf(n2, EPSf * EPSf));
  const float f = tanhf(n) / n;
  const float o = f * ve;
  yc[(size_t)row * Dd + t] = o;
  ychi[(size_t)row * Dd + t] = bhi(o);
}

// ---------------------------------------------------------------------------
// Final: mobius_matvec scaling (project), mobius_add with bias, project.
// ---------------------------------------------------------------------------
__global__ __launch_bounds__(768) void k_final(
    const float* __restrict__ yc, const float* __restrict__ mp,
    const float* __restrict__ bp, float* __restrict__ out) {
  const int t = threadIdx.x;
  const int row = blockIdx.x;
  const int w = t >> 6, lane = t & 63;
  __shared__ float red[12];
  auto blockSum = [&](float v) -> float {
    __syncthreads();
    const float s = wred64(v);
    if (lane == 0) red[w] = s;
    __syncthreads();
    float tot = 0.0f;
#pragma unroll
    for (int i = 0; i < 12; i++) tot += red[i];
    return tot;
  };
  const float xe = yc[(size_t)row * Dd + t];
  const float me = mp[(size_t)row * Dd + t];
  const float be = bp[t];
  const float xn2 = blockSum(xe * xe);
  const float xn = sqrtf(fmaxf(xn2, EPSf * EPSf));
  const float arx = artanh_(fminf(xn, MAXN));
  const float mn2 = blockSum(me * me);
  const float mxn = sqrtf(fmaxf(mn2, EPSf * EPSf));
  const float pn = tanhf(mxn / xn * arx);
  const float c1 = pn / mxn * fminf(1.0f, MAXN / fmaxf(pn, EPSf));
  const float mme = c1 * me;
  const float x2 = blockSum(mme * mme);
  const float y2 = blockSum(be * be);
  const float xy = blockSum(mme * be);
  const float nume = (1.0f + 2.0f * xy + y2) * mme + (1.0f - x2) * be;
  const float den = fmaxf(1.0f + 2.0f * xy + x2 * y2, EPSf);
  const float re = nume / den;
  const float rn2 = blockSum(re * re);
  const float rn = sqrtf(fmaxf(rn2, EPSf * EPSf));
  const float f = fminf(1.0f, MAXN / rn);
  out[(size_t)row * Dd + t] = f * re;
}

}  // namespace

extern "C" void kernel_launch(void* const* d_in, const int* in_sizes, int n_in,
                              void* d_out, int out_size, void* d_ws,
                              size_t ws_size, hipStream_t stream) {
  const float* x = (const float*)d_in[0];
  const float* Wq = (const float*)d_in[1];
  const float* Wk = (const float*)d_in[2];
  const float* Wv = (const float*)d_in[3];
  const float* Wp = (const float*)d_in[4];
  const float* bp = (const float*)d_in[5];
  const float* scale = (const float*)d_in[6];

  float* out = (float*)d_out;
  float* y_out = out;                        // (B,L,D)
  float* attn = out + (size_t)Bb * Ll * Dd;  // (B,H,L,L)

  const size_t NH = (size_t)Bb * Hh * Ll;  // 98304
  const size_t RD = (size_t)Bb * Ll * Dd;  // 6291456

  unsigned short* u = (unsigned short*)d_ws;
  unsigned short* qhh = u;
  unsigned short* qhl = u + RD;
  unsigned short* khh = u + 2 * RD;
  unsigned short* khl = u + 3 * RD;
  unsigned short* vth = u + 4 * RD;
  unsigned short* vtl = u + 5 * RD;
  unsigned short* vhh = u + 6 * RD;  // dead after k_vt
  unsigned short* vhl_ = u + 7 * RD;
  unsigned short* whi = u + 8 * RD;  // 4*DD ushorts (hi only)
  float* fb = (float*)(whi + 4 * (size_t)DDm);
  float* q2n = fb;
  float* k2n = fb + NH;
  float* lam1 = fb + 2 * NH;
  float* xn2a = fb + 3 * NH;  // 8192 floats
  // overlays (dead-region reuse after k_attn1):
  float* yh = (float*)(u + 6 * RD);   // RD floats over vhh/vhl_
  float* yc = (float*)u;              // RD floats over qhh/qhl
  unsigned short* ychi = u + 2 * RD;  // over khh
  float* mp = (float*)(u + 4 * RD);   // RD floats over vth/vtl

  // GEMM outputs + bf16 x staged in the not-yet-written attn region.
  float* mq = attn;
  float* mk = attn + RD;
  float* mv = attn + 2 * RD;
  unsigned short* xhi = (unsigned short*)(attn + 3 * RD);

  const double br =
      exp(lgamma(DHh / 2.0) + lgamma(0.5) - lgamma(DHh / 2.0 + 0.5) -
          (lgamma(Dd / 2.0) + lgamma(0.5) - lgamma(Dd / 2.0 + 0.5)));
  const float beta_ratio = (float)br;

  (void)in_sizes; (void)n_in; (void)out_size; (void)ws_size;

  k_cvtx<<<dim3(Bb * Ll), dim3(768), 0, stream>>>(x, xhi, xn2a);
  k_cvt4<<<dim3(DDm / 4 / 256, 1, 4), dim3(256), 0, stream>>>(Wq, Wk, Wv, Wp,
                                                              whi);

  k_gemm_bf16h<<<dim3(Dd / 128, (Bb * Ll) / 128, 3), dim3(256), 0, stream>>>(
      xhi, whi, mq);

  k_qkvt3<<<dim3(Bb * Ll, 3), dim3(768), 0, stream>>>(
      xn2a, mq, mk, mv, qhh, qhl, khh, khl, vhh, vhl_, q2n, k2n, lam1,
      beta_ratio);

  k_vt<<<dim3(16, Bb * Hh), dim3(256), 0, stream>>>(vhh, vhl_, vth, vtl);

  k_attn1<<<dim3(16, Bb * Hh), dim3(256), 0, stream>>>(
      qhh, qhl, khh, khl, vth, vtl, q2n, k2n, lam1, scale, attn, yh);

  k_concat<<<dim3(Bb * Ll), dim3(768), 0, stream>>>(yh, yc, ychi, beta_ratio);

  k_gemm_bf16h<<<dim3(Dd / 128, (Bb * Ll) / 128, 1), dim3(256), 0, stream>>>(
      ychi, whi + 3 * (size_t)DDm, mp);

  k_final<<<dim3(Bb * Ll), dim3(768), 0, stream>>>(yc, mp, bp, y_out);
}

// Round 15
// 612.018 us; speedup vs baseline: 1.0481x; 1.0481x over previous
//
#include <hip/hip_runtime.h>
#include <hip/hip_bf16.h>
#include <math.h>

namespace {

constexpr int Bb = 8, Ll = 1024, Dd = 768, Hh = 12, DHh = 64;
constexpr int DDm = Dd * Dd;
constexpr float MAXN = 1.0f - 1e-5f;
constexpr float EPSf = 1e-15f;

typedef __attribute__((ext_vector_type(8))) short short8;
typedef __attribute__((ext_vector_type(4))) short short4v;
typedef __attribute__((ext_vector_type(4))) float f32x4;

__device__ __forceinline__ float wred64(float v) {
#pragma unroll
  for (int m = 32; m >= 1; m >>= 1) v += __shfl_xor(v, m, 64);
  return v;
}

__device__ __forceinline__ float artanh_(float x) {
  return 0.5f * logf((1.0f + x) / (1.0f - x));
}

__device__ __forceinline__ void bsplit(float x, unsigned short& h,
                                       unsigned short& l) {
  __hip_bfloat16 hb = __float2bfloat16(x);
  const float hf = __bfloat162float(hb);
  __hip_bfloat16 lb = __float2bfloat16(x - hf);
  h = *(unsigned short*)&hb;
  l = *(unsigned short*)&lb;
}

__device__ __forceinline__ unsigned short bhi(float x) {
  __hip_bfloat16 hb = __float2bfloat16(x);
  return *(unsigned short*)&hb;
}

__device__ __forceinline__ float bf2f(unsigned short u) {
  union { unsigned int i; float f; } cv;
  cv.i = ((unsigned int)u) << 16;
  return cv.f;
}

// Async global->LDS 16B DMA (gfx950). LDS dest must be wave-uniform base +
// lane*16 (linear in lane order) — swizzling is done on the SOURCE address.
__device__ __forceinline__ void gll16(const unsigned short* g,
                                      unsigned short* l) {
  __builtin_amdgcn_global_load_lds(
      (const __attribute__((address_space(1))) void*)g,
      (__attribute__((address_space(3))) void*)l, 16, 0, 0);
}

// ---------------------------------------------------------------------------
// x -> bf16 (hi only, for GEMM A) + per-row squared norm.
// ---------------------------------------------------------------------------
__global__ __launch_bounds__(768) void k_cvtx(const float* __restrict__ x,
                                              unsigned short* __restrict__ hi,
                                              float* __restrict__ xn2a) {
  const int t = threadIdx.x;
  const int row = blockIdx.x;
  const int w = t >> 6, lane = t & 63;
  __shared__ float red[12];
  const float xe = x[(size_t)row * Dd + t];
  hi[(size_t)row * Dd + t] = bhi(xe);
  const float s = wred64(xe * xe);
  if (lane == 0) red[w] = s;
  __syncthreads();
  if (t == 0) {
    float tot = 0.0f;
#pragma unroll
    for (int i = 0; i < 12; i++) tot += red[i];
    xn2a[row] = tot;
  }
}

// 4 weight matrices -> bf16 hi in one launch (blockIdx.z selects source).
__global__ __launch_bounds__(256) void k_cvt4(
    const float* __restrict__ w0, const float* __restrict__ w1,
    const float* __restrict__ w2, const float* __restrict__ w3,
    unsigned short* __restrict__ hi) {
  const int z = blockIdx.z;
  const float* in = (z == 0) ? w0 : (z == 1) ? w1 : (z == 2) ? w2 : w3;
  const int i = blockIdx.x * 256 + threadIdx.x;
  if (i >= DDm / 4) return;
  float4 v = ((const float4*)in)[i];
  ((ushort4*)(hi + (size_t)z * DDm))[i] =
      make_ushort4(bhi(v.x), bhi(v.y), bhi(v.z), bhi(v.w));
}

// ---------------------------------------------------------------------------
// Pure-bf16 MFMA GEMM: C = A @ W^T. m97-shape: 4 global_load_lds (16B DMA,
// source-side swizzle) + 8 ds_read_b128 + 16 MFMA per K-step. 16 KB LDS.
// ---------------------------------------------------------------------------
__global__ __launch_bounds__(256) void k_gemm_bf16h(
    const unsigned short* __restrict__ Ahi,
    const unsigned short* __restrict__ Whi, float* __restrict__ C) {
  constexpr int K = Dd, N = Dd;
  const int z = blockIdx.z;
  const unsigned short* Bh = Whi + (size_t)z * DDm;
  float* Cz = C + (size_t)z * 8192 * N;
  __shared__ __align__(16) unsigned short sAh[128 * 32];
  __shared__ __align__(16) unsigned short sBh[128 * 32];
  const int t = threadIdx.x;
  const int l = t & 63, wid = t >> 6;
  const int wr = wid >> 1, wc = wid & 1;
  const int m0 = blockIdx.y * 128, n0 = blockIdx.x * 128;

  const int r0 = t >> 2;
  const int kfs = ((t & 3) ^ ((r0 >> 1) & 3)) << 3;
  const size_t ga0 = (size_t)(m0 + r0) * K + kfs;
  const size_t ga1 = (size_t)(m0 + r0 + 64) * K + kfs;
  const size_t gb0 = (size_t)(n0 + r0) * K + kfs;
  const size_t gb1 = (size_t)(n0 + r0 + 64) * K + kfs;
  unsigned short* dA0 = &sAh[t * 8];
  unsigned short* dA1 = &sAh[(t + 256) * 8];
  unsigned short* dB0 = &sBh[t * 8];
  unsigned short* dB1 = &sBh[(t + 256) * 8];

  const int lar = l & 15, lkf = l >> 4;

  f32x4 acc[4][4] = {};

  for (int k0 = 0; k0 < K; k0 += 32) {
    __syncthreads();  // prior iteration's LDS reads complete
    gll16(&Ahi[ga0 + k0], dA0);
    gll16(&Ahi[ga1 + k0], dA1);
    gll16(&Bh[gb0 + k0], dB0);
    gll16(&Bh[gb1 + k0], dB1);
    __syncthreads();  // vmcnt drained -> staging visible

    short8 ah[4], bh[4];
#pragma unroll
    for (int f = 0; f < 4; f++) {
      const int ra = wr * 64 + f * 16 + lar;
      const int ia = ra * 32 + ((lkf ^ ((ra >> 1) & 3)) << 3);
      ah[f] = *(const short8*)&sAh[ia];
      const int rb = wc * 64 + f * 16 + lar;
      const int ib = rb * 32 + ((lkf ^ ((rb >> 1) & 3)) << 3);
      bh[f] = *(const short8*)&sBh[ib];
    }
#pragma unroll
    for (int i = 0; i < 4; i++)
#pragma unroll
      for (int j = 0; j < 4; j++)
        acc[i][j] = __builtin_amdgcn_mfma_f32_16x16x32_bf16(ah[i], bh[j],
                                                            acc[i][j], 0, 0, 0);
  }

#pragma unroll
  for (int i = 0; i < 4; i++)
#pragma unroll
    for (int j = 0; j < 4; j++) {
      const int row = m0 + wr * 64 + i * 16 + (l >> 4) * 4;
      const int col = n0 + wc * 64 + j * 16 + (l & 15);
      const f32x4 v = acc[i][j];
#pragma unroll
      for (int q = 0; q < 4; q++) Cz[(size_t)(row + q) * N + col] = v[q];
    }
}

// ---------------------------------------------------------------------------
// Per-row transform, one (row, mi) per block. Emits q/k as bf16 hi/lo,
// lam*v as bf16 hi only, + per-head stats.
// ---------------------------------------------------------------------------
__global__ __launch_bounds__(768) void k_qkvt3(
    const float* __restrict__ xn2a,
    const float* __restrict__ mq, const float* __restrict__ mk,
    const float* __restrict__ mv,
    unsigned short* __restrict__ qhh, unsigned short* __restrict__ qhl,
    unsigned short* __restrict__ khh, unsigned short* __restrict__ khl,
    unsigned short* __restrict__ vhh,
    float* __restrict__ q2n, float* __restrict__ k2n,
    float* __restrict__ lam1, float beta_ratio) {
  const int t = threadIdx.x;
  const int row = blockIdx.x;  // b*L + l
  const int mi = blockIdx.y;
  const int b = row >> 10, l = row & 1023;
  const int w = t >> 6, lane = t & 63;
  __shared__ float red[12];

  const float* m = (mi == 0) ? mq : (mi == 1) ? mk : mv;
  const float me = m[(size_t)row * Dd + t];
  const float s2 = wred64(me * me);
  if (lane == 0) red[w] = s2;
  __syncthreads();
  float mn2 = 0.0f;
#pragma unroll
  for (int i = 0; i < 12; i++) mn2 += red[i];

  const float xn = sqrtf(fmaxf(xn2a[row], EPSf * EPSf));
  const float arx = artanh_(fminf(xn, MAXN));

  const float mxn = sqrtf(fmaxf(mn2, EPSf * EPSf));
  const float pn = tanhf(mxn / xn * arx);
  const float c1 = pn / mxn * fminf(1.0f, MAXN / fmaxf(pn, EPSf));
  const float nn = fmaxf(fminf(pn, MAXN), EPSf);
  const float c2 = artanh_(nn) / nn;
  const float ve = c2 * c1 * me * beta_ratio;
  const float hs = wred64(ve * ve);
  const float hn = sqrtf(fmaxf(hs, EPSf * EPSf));
  const float th = tanhf(hn);
  const float oe = th / hn * ve;
  const size_t hidx = (size_t)(b * Hh + w) * Ll + l;
  const size_t oidx = hidx * DHh + lane;
  unsigned short hu, lu;
  if (mi == 0) {
    bsplit(oe, hu, lu);
    qhh[oidx] = hu; qhl[oidx] = lu;
    if (lane == 0) q2n[hidx] = th * th;
  } else if (mi == 1) {
    bsplit(oe, hu, lu);
    khh[oidx] = hu; khl[oidx] = lu;
    if (lane == 0) k2n[hidx] = th * th;
  } else {
    const float lam = 2.0f / fmaxf(1.0f - th * th, EPSf);
    vhh[oidx] = bhi(lam * oe);
    if (lane == 0) lam1[hidx] = lam - 1.0f;
  }
}

// ---------------------------------------------------------------------------
// Transpose lam*v per head: [k][d] -> [d][k] (bf16 hi only).
// ---------------------------------------------------------------------------
__global__ __launch_bounds__(256) void k_vt(const unsigned short* __restrict__ vh,
                                            unsigned short* __restrict__ th) {
  __shared__ __align__(16) unsigned short sh[64 * 72];
  const int t = threadIdx.x;
  const int bh = blockIdx.y, c = blockIdx.x;
  const size_t ibase = ((size_t)bh * Ll + c * 64) * DHh;
#pragma unroll
  for (int u = 0; u < 2; u++) {
    const int ch = t + u * 256, r = ch >> 3, f = ch & 7;
    *(short8*)&sh[r * 72 + f * 8] = *(const short8*)&vh[ibase + r * DHh + f * 8];
  }
  __syncthreads();
#pragma unroll
  for (int u = 0; u < 2; u++) {
    const int ch = t + u * 256, d = ch >> 3, kb = ch & 7;
    short8 oh;
#pragma unroll
    for (int i = 0; i < 8; i++) oh[i] = (short)sh[(kb * 8 + i) * 72 + d];
    const size_t ob = ((size_t)bh * DHh + d) * Ll + c * 64 + kb * 8;
    *(short8*)&th[ob] = oh;
  }
}

// ---------------------------------------------------------------------------
// Fused attention, SINGLE pass, DOUBLE-BUFFERED LDS -> one barrier/chunk.
// Iter c: write buf[c&1] -> prefetch c+1 regs -> barrier -> compute buf[c&1].
// Reads of buf[p] (iter c) are separated from the next write of buf[p]
// (iter c+2) by the iter-c+1 barrier; __syncthreads drains lgkm/vm counts.
// Score via the 1-t^2 identity (per-q-row constant cancels). PV uses V hi
// only (yc is bf16-rounded before proj GEMM anyway). Writes bf16(e) into
// first half of each fp32 attn row; k_norm expands+normalizes.
// ---------------------------------------------------------------------------
__global__ __launch_bounds__(256) void k_attn1(
    const unsigned short* __restrict__ qhh, const unsigned short* __restrict__ qhl,
    const unsigned short* __restrict__ khh, const unsigned short* __restrict__ khl,
    const unsigned short* __restrict__ vth,
    const float* __restrict__ q2n, const float* __restrict__ k2n,
    const float* __restrict__ lam1, const float* __restrict__ scale_p,
    float* __restrict__ attn, float* __restrict__ rowsum,
    float* __restrict__ yh) {
  __shared__ __align__(16) unsigned short kldsh[2][32 * 72];
  __shared__ __align__(16) unsigned short kldsl[2][32 * 72];
  __shared__ __align__(16) unsigned short vldsh[2][64 * 36];
  __shared__ __align__(16) unsigned short wlds[4][16 * 36];
  __shared__ __align__(16) float k2s[2][32];
  __shared__ __align__(16) float l1s[2][32];
  __shared__ __align__(16) float ik2s[2][32];
  __shared__ float dred[4][16];
  const int t = threadIdx.x, l = t & 63, w = t >> 6;
  const int lr = l & 15, lg = l >> 4;
  const int bh = blockIdx.y, q0 = blockIdx.x * 64;
  const size_t hbase = (size_t)bh * Ll;
  const float scale = scale_p[0];
  const bool sone = (scale == 1.0f);

  short8 aqh[2], aql[2];
#pragma unroll
  for (int s = 0; s < 2; s++) {
    const size_t off = (hbase + q0 + w * 16 + lr) * (size_t)DHh + s * 32 + lg * 8;
    aqh[s] = *(const short8*)&qhh[off];
    aql[s] = *(const short8*)&qhl[off];
  }
  const float q2v = q2n[hbase + q0 + w * 16 + lr];

  const int kr = t >> 3, kf = t & 7;
  const int vd = t >> 2, vf = t & 3;

  float rs = 0.0f, dacc = 0.0f;
  f32x4 pv[4] = {};

  short8 pkh, pkl, pvh;
  float k2r = 0.0f, l1r = 0.0f;
  auto load_chunk = [&](int c) {
    const size_t kg = (hbase + c * 32 + kr) * (size_t)DHh + kf * 8;
    pkh = *(const short8*)&khh[kg];
    pkl = *(const short8*)&khl[kg];
    const size_t vg = ((size_t)bh * DHh + vd) * (size_t)Ll + c * 32 + vf * 8;
    pvh = *(const short8*)&vth[vg];
    if (t < 32) {
      k2r = k2n[hbase + c * 32 + t];
      l1r = lam1[hbase + c * 32 + t];
    }
  };
  load_chunk(0);

  for (int c = 0; c < 32; c++) {
    const int pb = c & 1;
    // Stage chunk c into buffer pb (regs were loaded in prior iteration).
    *(short8*)&kldsh[pb][kr * 72 + kf * 8] = pkh;
    *(short8*)&kldsl[pb][kr * 72 + kf * 8] = pkl;
    *(short8*)&vldsh[pb][vd * 36 + vf * 8] = pvh;
    if (t < 32) {
      k2s[pb][t] = k2r;
      l1s[pb][t] = l1r;
      ik2s[pb][t] = __builtin_amdgcn_rcpf(1.0f - k2r);
    }
    if (c + 1 < 32) load_chunk(c + 1);  // prefetch c+1 (regs only)
    __syncthreads();  // writes visible; prior reads of buf pb (c-2) done

#pragma unroll
    for (int j = 0; j < 2; j++) {
      f32x4 acc = {};
#pragma unroll
      for (int s = 0; s < 2; s++) {
        const int ko = (j * 16 + lr) * 72 + s * 32 + lg * 8;
        const short8 kfh = *(const short8*)&kldsh[pb][ko];
        const short8 kfl = *(const short8*)&kldsl[pb][ko];
        acc = __builtin_amdgcn_mfma_f32_16x16x32_bf16(kfh, aqh[s], acc, 0, 0, 0);
        acc = __builtin_amdgcn_mfma_f32_16x16x32_bf16(kfh, aql[s], acc, 0, 0, 0);
        acc = __builtin_amdgcn_mfma_f32_16x16x32_bf16(kfl, aqh[s], acc, 0, 0, 0);
      }
      const float4 k2q = *(const float4*)&k2s[pb][j * 16 + lg * 4];
      const float4 l1q = *(const float4*)&l1s[pb][j * 16 + lg * 4];
      const float4 ikq = *(const float4*)&ik2s[pb][j * 16 + lg * 4];
      const float kq[4] = {k2q.x, k2q.y, k2q.z, k2q.w};
      const float lq[4] = {l1q.x, l1q.y, l1q.z, l1q.w};
      const float iq[4] = {ikq.x, ikq.y, ikq.z, ikq.w};
      short4v wv;
#pragma unroll
      for (int r = 0; r < 4; r++) {
        const float qk2 = acc[r] + acc[r];
        const float d = fmaxf(q2v + kq[r] - qk2, 0.0f);
        const float dn = fmaf(q2v, kq[r], 1.0f) - qk2;  // > 0.5 here
        const float m_ = fmaxf(d * dn, 1e-30f);
        const float s_ = m_ * __builtin_amdgcn_rsqf(m_);  // sqrt(d*dn)
        float e = (dn + d - s_ - s_) * iq[r];  // p*(1-q2) >= 0
        if (!sone) e = expf(scale * logf(fmaxf(e, 1e-30f)));
        rs += e;
        __hip_bfloat16 eb = __float2bfloat16(e);
        wv[r] = *(short*)&eb;
        dacc += __bfloat162float(eb) * lq[r];  // den from SAME rounded w
      }
      *(short4v*)&wlds[w][lr * 36 + j * 16 + lg * 4] = wv;
    }
    // PV: A = w (16q x 32k, bf16, wave-local), B = (lam v)^T hi [d][k].
    {
      const short8 wa = *(const short8*)&wlds[w][lr * 36 + lg * 8];
#pragma unroll
      for (int n = 0; n < 4; n++) {
        const short8 vbh8 = *(const short8*)&vldsh[pb][(n * 16 + lr) * 36 + lg * 8];
        pv[n] = __builtin_amdgcn_mfma_f32_16x16x32_bf16(wa, vbh8, pv[n], 0, 0, 0);
      }
    }
    // Coalesced bf16-e store: wave-local re-read of wlds, 16B per lane.
    {
      const int qy = l >> 2, cg = l & 3;
      const short8 ev = *(const short8*)&wlds[w][qy * 36 + cg * 8];
      unsigned short* eb =
          (unsigned short*)(attn + (hbase + q0 + w * 16 + qy) * (size_t)Ll);
      *(short8*)&eb[c * 32 + cg * 8] = ev;
    }
  }

  rs += __shfl_xor(rs, 16, 64);
  rs += __shfl_xor(rs, 32, 64);
  if (lg == 0) rowsum[hbase + q0 + w * 16 + lr] = rs;

  dacc += __shfl_xor(dacc, 16, 64);
  dacc += __shfl_xor(dacc, 32, 64);
  if (lg == 0) dred[w][lr] = dacc;

  const int b = bh / Hh, h = bh % Hh;
#pragma unroll
  for (int r = 0; r < 4; r++) {
    float den = dred[w][lg * 4 + r];
    if (fabsf(den) < 1e-10f) den = 1e-10f;
    const float dinv = 1.0f / den;
    float tm[4];
    float n2 = 0.0f;
#pragma unroll
    for (int n = 0; n < 4; n++) {
      tm[n] = pv[n][r] * dinv;
      n2 += tm[n] * tm[n];
    }
    n2 += __shfl_xor(n2, 1, 64);
    n2 += __shfl_xor(n2, 2, 64);
    n2 += __shfl_xor(n2, 4, 64);
    n2 += __shfl_xor(n2, 8, 64);
    const float nn = sqrtf(fmaxf(n2, EPSf * EPSf));
    const float nc = fminf(nn, MAXN);
    const float pn = nc / (1.0f + sqrtf(fmaxf(1.0f - nc * nc, 0.0f)));
    const float f = pn / nn * fminf(1.0f, MAXN / fmaxf(pn, EPSf));
    const int ql = q0 + w * 16 + lg * 4 + r;
#pragma unroll
    for (int n = 0; n < 4; n++)
      yh[(((size_t)(b * Ll + ql)) * Hh + h) * DHh + n * 16 + lr] = f * tm[n];
  }
}

// ---------------------------------------------------------------------------
// Normalize + expand: one row per block. Row's bf16 e values occupy the
// first 2 KB of the 4 KB fp32 row; read all (registers), sync, write fp32.
// ---------------------------------------------------------------------------
__global__ __launch_bounds__(256) void k_norm(float* __restrict__ attn,
                                              const float* __restrict__ rowsum) {
  const int row = blockIdx.x;
  const float rinv = 1.0f / rowsum[row];
  float* prow = attn + (size_t)row * Ll;
  const ushort4 u4 = ((const ushort4*)prow)[threadIdx.x];  // 4 bf16 e
  __syncthreads();  // all reads done before in-place expansion writes
  float4 v;
  v.x = bf2f(u4.x) * rinv;
  v.y = bf2f(u4.y) * rinv;
  v.z = bf2f(u4.z) * rinv;
  v.w = bf2f(u4.w) * rinv;
  ((float4*)prow)[threadIdx.x] = v;
}

// ---------------------------------------------------------------------------
// beta_concat: per-head logmap0 / BETA_RATIO, then expmap0 over full D.
// Also emits the bf16 (hi-only) copy of yc for the projection GEMM.
// ---------------------------------------------------------------------------
__global__ __launch_bounds__(768) void k_concat(
    const float* __restrict__ yh, float* __restrict__ yc,
    unsigned short* __restrict__ ychi, float beta_ratio) {
  const int t = threadIdx.x;
  const int row = blockIdx.x;
  const int w = t >> 6, lane = t & 63;
  __shared__ float red[12];
  const float ye = yh[(size_t)row * Dd + t];
  const float hs = wred64(ye * ye);
  const float hn = sqrtf(fmaxf(hs, EPSf * EPSf));
  const float cc = artanh_(fminf(hn, MAXN)) / hn / beta_ratio;
  const float ve = cc * ye;
  const float s = wred64(ve * ve);
  if (lane == 0) red[w] = s;
  __syncthreads();
  float n2 = 0.0f;
#pragma unroll
  for (int i = 0; i < 12; i++) n2 += red[i];
  const float n = sqrtf(fmaxf(n2, EPSf * EPSf));
  const float f = tanhf(n) / n;
  const float o = f * ve;
  yc[(size_t)row * Dd + t] = o;
  ychi[(size_t)row * Dd + t] = bhi(o);
}

// ---------------------------------------------------------------------------
// Final: mobius_matvec scaling (project), mobius_add with bias, project.
// ---------------------------------------------------------------------------
__global__ __launch_bounds__(768) void k_final(
    const float* __restrict__ yc, const float* __restrict__ mp,
    const float* __restrict__ bp, float* __restrict__ out) {
  const int t = threadIdx.x;
  const int row = blockIdx.x;
  const int w = t >> 6, lane = t & 63;
  __shared__ float red[12];
  auto blockSum = [&](float v) -> float {
    __syncthreads();
    const float s = wred64(v);
    if (lane == 0) red[w] = s;
    __syncthreads();
    float tot = 0.0f;
#pragma unroll
    for (int i = 0; i < 12; i++) tot += red[i];
    return tot;
  };
  const float xe = yc[(size_t)row * Dd + t];
  const float me = mp[(size_t)row * Dd + t];
  const float be = bp[t];
  const float xn2 = blockSum(xe * xe);
  const float xn = sqrtf(fmaxf(xn2, EPSf * EPSf));
  const float arx = artanh_(fminf(xn, MAXN));
  const float mn2 = blockSum(me * me);
  const float mxn = sqrtf(fmaxf(mn2, EPSf * EPSf));
  const float pn = tanhf(mxn / xn * arx);
  const float c1 = pn / mxn * fminf(1.0f, MAXN / fmaxf(pn, EPSf));
  const float mme = c1 * me;
  const float x2 = blockSum(mme * mme);
  const float y2 = blockSum(be * be);
  const float xy = blockSum(mme * be);
  const float nume = (1.0f + 2.0f * xy + y2) * mme + (1.0f - x2) * be;
  const float den = fmaxf(1.0f + 2.0f * xy + x2 * y2, EPSf);
  const float re = nume / den;
  const float rn2 = blockSum(re * re);
  const float rn = sqrtf(fmaxf(rn2, EPSf * EPSf));
  const float f = fminf(1.0f, MAXN / rn);
  out[(size_t)row * Dd + t] = f * re;
}

}  // namespace

extern "C" void kernel_launch(void* const* d_in, const int* in_sizes, int n_in,
                              void* d_out, int out_size, void* d_ws,
                              size_t ws_size, hipStream_t stream) {
  const float* x = (const float*)d_in[0];
  const float* Wq = (const float*)d_in[1];
  const float* Wk = (const float*)d_in[2];
  const float* Wv = (const float*)d_in[3];
  const float* Wp = (const float*)d_in[4];
  const float* bp = (const float*)d_in[5];
  const float* scale = (const float*)d_in[6];

  float* out = (float*)d_out;
  float* y_out = out;                        // (B,L,D)
  float* attn = out + (size_t)Bb * Ll * Dd;  // (B,H,L,L)

  const size_t NH = (size_t)Bb * Hh * Ll;  // 98304
  const size_t RD = (size_t)Bb * Ll * Dd;  // 6291456

  unsigned short* u = (unsigned short*)d_ws;
  unsigned short* qhh = u;
  unsigned short* qhl = u + RD;
  unsigned short* khh = u + 2 * RD;
  unsigned short* khl = u + 3 * RD;
  unsigned short* vth = u + 4 * RD;
  unsigned short* vhh = u + 6 * RD;  // dead after k_vt
  unsigned short* whi = u + 8 * RD;  // 4*DD ushorts (hi only)
  float* fb = (float*)(whi + 4 * (size_t)DDm);
  float* q2n = fb;
  float* k2n = fb + NH;
  float* lam1 = fb + 2 * NH;
  float* rowsum = fb + 3 * NH;
  float* xn2a = fb + 4 * NH;  // 8192 floats
  // overlays (dead-region reuse after k_attn1):
  float* yh = (float*)(u + 6 * RD);   // RD floats over vhh region
  float* yc = (float*)u;              // RD floats over qhh/qhl
  unsigned short* ychi = u + 2 * RD;  // over khh
  float* mp = (float*)(u + 4 * RD);   // RD floats over vth region

  // GEMM outputs + bf16 x staged in the not-yet-written attn region.
  float* mq = attn;
  float* mk = attn + RD;
  float* mv = attn + 2 * RD;
  unsigned short* xhi = (unsigned short*)(attn + 3 * RD);

  const double br =
      exp(lgamma(DHh / 2.0) + lgamma(0.5) - lgamma(DHh / 2.0 + 0.5) -
          (lgamma(Dd / 2.0) + lgamma(0.5) - lgamma(Dd / 2.0 + 0.5)));
  const float beta_ratio = (float)br;

  (void)in_sizes; (void)n_in; (void)out_size; (void)ws_size;

  k_cvtx<<<dim3(Bb * Ll), dim3(768), 0, stream>>>(x, xhi, xn2a);
  k_cvt4<<<dim3(DDm / 4 / 256, 1, 4), dim3(256), 0, stream>>>(Wq, Wk, Wv, Wp,
                                                              whi);

  k_gemm_bf16h<<<dim3(Dd / 128, (Bb * Ll) / 128, 3), dim3(256), 0, stream>>>(
      xhi, whi, mq);

  k_qkvt3<<<dim3(Bb * Ll, 3), dim3(768), 0, stream>>>(
      xn2a, mq, mk, mv, qhh, qhl, khh, khl, vhh, q2n, k2n, lam1, beta_ratio);

  k_vt<<<dim3(16, Bb * Hh), dim3(256), 0, stream>>>(vhh, vth);

  k_attn1<<<dim3(16, Bb * Hh), dim3(256), 0, stream>>>(
      qhh, qhl, khh, khl, vth, q2n, k2n, lam1, scale, attn, rowsum, yh);

  k_norm<<<dim3((int)NH), dim3(256), 0, stream>>>(attn, rowsum);

  k_concat<<<dim3(Bb * Ll), dim3(768), 0, stream>>>(yh, yc, ychi, beta_ratio);

  k_gemm_bf16h<<<dim3(Dd / 128, (Bb * Ll) / 128, 1), dim3(256), 0, stream>>>(
      ychi, whi + 3 * (size_t)DDm, mp);

  k_final<<<dim3(Bb * Ll), dim3(768), 0, stream>>>(yc, mp, bp, y_out);
}

// Round 16
// 594.042 us; speedup vs baseline: 1.0798x; 1.0303x over previous
//
#include <hip/hip_runtime.h>
#include <hip/hip_bf16.h>
#include <math.h>

namespace {

constexpr int Bb = 8, Ll = 1024, Dd = 768, Hh = 12, DHh = 64;
constexpr int DDm = Dd * Dd;
constexpr float MAXN = 1.0f - 1e-5f;
constexpr float EPSf = 1e-15f;

typedef __attribute__((ext_vector_type(8))) short short8;
typedef __attribute__((ext_vector_type(4))) short short4v;
typedef __attribute__((ext_vector_type(4))) float f32x4;

__device__ __forceinline__ float wred64(float v) {
#pragma unroll
  for (int m = 32; m >= 1; m >>= 1) v += __shfl_xor(v, m, 64);
  return v;
}

__device__ __forceinline__ float artanh_(float x) {
  return 0.5f * logf((1.0f + x) / (1.0f - x));
}

__device__ __forceinline__ void bsplit(float x, unsigned short& h,
                                       unsigned short& l) {
  __hip_bfloat16 hb = __float2bfloat16(x);
  const float hf = __bfloat162float(hb);
  __hip_bfloat16 lb = __float2bfloat16(x - hf);
  h = *(unsigned short*)&hb;
  l = *(unsigned short*)&lb;
}

__device__ __forceinline__ unsigned short bhi(float x) {
  __hip_bfloat16 hb = __float2bfloat16(x);
  return *(unsigned short*)&hb;
}

__device__ __forceinline__ float bf2f(unsigned short u) {
  union { unsigned int i; float f; } cv;
  cv.i = ((unsigned int)u) << 16;
  return cv.f;
}

// Async global->LDS 16B DMA (gfx950). LDS dest must be wave-uniform base +
// lane*16 (linear in lane order) — swizzling is done on the SOURCE address.
__device__ __forceinline__ void gll16(const unsigned short* g,
                                      unsigned short* l) {
  __builtin_amdgcn_global_load_lds(
      (const __attribute__((address_space(1))) void*)g,
      (__attribute__((address_space(3))) void*)l, 16, 0, 0);
}

// ---------------------------------------------------------------------------
// x -> bf16 (hi only, for GEMM A) + per-row squared norm.
// ---------------------------------------------------------------------------
__global__ __launch_bounds__(768) void k_cvtx(const float* __restrict__ x,
                                              unsigned short* __restrict__ hi,
                                              float* __restrict__ xn2a) {
  const int t = threadIdx.x;
  const int row = blockIdx.x;
  const int w = t >> 6, lane = t & 63;
  __shared__ float red[12];
  const float xe = x[(size_t)row * Dd + t];
  hi[(size_t)row * Dd + t] = bhi(xe);
  const float s = wred64(xe * xe);
  if (lane == 0) red[w] = s;
  __syncthreads();
  if (t == 0) {
    float tot = 0.0f;
#pragma unroll
    for (int i = 0; i < 12; i++) tot += red[i];
    xn2a[row] = tot;
  }
}

// 4 weight matrices -> bf16 hi in one launch (blockIdx.z selects source).
__global__ __launch_bounds__(256) void k_cvt4(
    const float* __restrict__ w0, const float* __restrict__ w1,
    const float* __restrict__ w2, const float* __restrict__ w3,
    unsigned short* __restrict__ hi) {
  const int z = blockIdx.z;
  const float* in = (z == 0) ? w0 : (z == 1) ? w1 : (z == 2) ? w2 : w3;
  const int i = blockIdx.x * 256 + threadIdx.x;
  if (i >= DDm / 4) return;
  float4 v = ((const float4*)in)[i];
  ((ushort4*)(hi + (size_t)z * DDm))[i] =
      make_ushort4(bhi(v.x), bhi(v.y), bhi(v.z), bhi(v.w));
}

// ---------------------------------------------------------------------------
// Pure-bf16 MFMA GEMM: C = A @ W^T. m97-shape, XCD-chunked block swizzle
// (bijective, nwg % 8 == 0) so A-panel re-readers share one XCD L2.
// ---------------------------------------------------------------------------
__global__ __launch_bounds__(256) void k_gemm_bf16h(
    const unsigned short* __restrict__ Ahi,
    const unsigned short* __restrict__ Whi, float* __restrict__ C) {
  constexpr int K = Dd, N = Dd;
  // XCD swizzle: consecutive WORK ids land on the same XCD chunk.
  const int gxy = gridDim.x * gridDim.y;
  const int nwg = gxy * gridDim.z;
  const int lin = (blockIdx.z * gridDim.y + blockIdx.y) * gridDim.x + blockIdx.x;
  const int work = (lin & 7) * (nwg >> 3) + (lin >> 3);
  const int z = work / gxy;
  const int rem = work - z * gxy;
  const int by = rem / gridDim.x;
  const int bx = rem - by * gridDim.x;

  const unsigned short* Bh = Whi + (size_t)z * DDm;
  float* Cz = C + (size_t)z * 8192 * N;
  __shared__ __align__(16) unsigned short sAh[128 * 32];
  __shared__ __align__(16) unsigned short sBh[128 * 32];
  const int t = threadIdx.x;
  const int l = t & 63, wid = t >> 6;
  const int wr = wid >> 1, wc = wid & 1;
  const int m0 = by * 128, n0 = bx * 128;

  const int r0 = t >> 2;
  const int kfs = ((t & 3) ^ ((r0 >> 1) & 3)) << 3;
  const size_t ga0 = (size_t)(m0 + r0) * K + kfs;
  const size_t ga1 = (size_t)(m0 + r0 + 64) * K + kfs;
  const size_t gb0 = (size_t)(n0 + r0) * K + kfs;
  const size_t gb1 = (size_t)(n0 + r0 + 64) * K + kfs;
  unsigned short* dA0 = &sAh[t * 8];
  unsigned short* dA1 = &sAh[(t + 256) * 8];
  unsigned short* dB0 = &sBh[t * 8];
  unsigned short* dB1 = &sBh[(t + 256) * 8];

  const int lar = l & 15, lkf = l >> 4;

  f32x4 acc[4][4] = {};

  for (int k0 = 0; k0 < K; k0 += 32) {
    __syncthreads();  // prior iteration's LDS reads complete
    gll16(&Ahi[ga0 + k0], dA0);
    gll16(&Ahi[ga1 + k0], dA1);
    gll16(&Bh[gb0 + k0], dB0);
    gll16(&Bh[gb1 + k0], dB1);
    __syncthreads();  // vmcnt drained -> staging visible

    short8 ah[4], bh[4];
#pragma unroll
    for (int f = 0; f < 4; f++) {
      const int ra = wr * 64 + f * 16 + lar;
      const int ia = ra * 32 + ((lkf ^ ((ra >> 1) & 3)) << 3);
      ah[f] = *(const short8*)&sAh[ia];
      const int rb = wc * 64 + f * 16 + lar;
      const int ib = rb * 32 + ((lkf ^ ((rb >> 1) & 3)) << 3);
      bh[f] = *(const short8*)&sBh[ib];
    }
#pragma unroll
    for (int i = 0; i < 4; i++)
#pragma unroll
      for (int j = 0; j < 4; j++)
        acc[i][j] = __builtin_amdgcn_mfma_f32_16x16x32_bf16(ah[i], bh[j],
                                                            acc[i][j], 0, 0, 0);
  }

#pragma unroll
  for (int i = 0; i < 4; i++)
#pragma unroll
    for (int j = 0; j < 4; j++) {
      const int row = m0 + wr * 64 + i * 16 + (l >> 4) * 4;
      const int col = n0 + wc * 64 + j * 16 + (l & 15);
      const f32x4 v = acc[i][j];
#pragma unroll
      for (int q = 0; q < 4; q++) Cz[(size_t)(row + q) * N + col] = v[q];
    }
}

// ---------------------------------------------------------------------------
// Per-row transform, one (row, mi) per block. Emits q/k as bf16 hi/lo,
// lam*v as bf16 hi only, + per-head stats.
// ---------------------------------------------------------------------------
__global__ __launch_bounds__(768) void k_qkvt3(
    const float* __restrict__ xn2a,
    const float* __restrict__ mq, const float* __restrict__ mk,
    const float* __restrict__ mv,
    unsigned short* __restrict__ qhh, unsigned short* __restrict__ qhl,
    unsigned short* __restrict__ khh, unsigned short* __restrict__ khl,
    unsigned short* __restrict__ vhh,
    float* __restrict__ q2n, float* __restrict__ k2n,
    float* __restrict__ lam1, float beta_ratio) {
  const int t = threadIdx.x;
  const int row = blockIdx.x;  // b*L + l
  const int mi = blockIdx.y;
  const int b = row >> 10, l = row & 1023;
  const int w = t >> 6, lane = t & 63;
  __shared__ float red[12];

  const float* m = (mi == 0) ? mq : (mi == 1) ? mk : mv;
  const float me = m[(size_t)row * Dd + t];
  const float s2 = wred64(me * me);
  if (lane == 0) red[w] = s2;
  __syncthreads();
  float mn2 = 0.0f;
#pragma unroll
  for (int i = 0; i < 12; i++) mn2 += red[i];

  const float xn = sqrtf(fmaxf(xn2a[row], EPSf * EPSf));
  const float arx = artanh_(fminf(xn, MAXN));

  const float mxn = sqrtf(fmaxf(mn2, EPSf * EPSf));
  const float pn = tanhf(mxn / xn * arx);
  const float c1 = pn / mxn * fminf(1.0f, MAXN / fmaxf(pn, EPSf));
  const float nn = fmaxf(fminf(pn, MAXN), EPSf);
  const float c2 = artanh_(nn) / nn;
  const float ve = c2 * c1 * me * beta_ratio;
  const float hs = wred64(ve * ve);
  const float hn = sqrtf(fmaxf(hs, EPSf * EPSf));
  const float th = tanhf(hn);
  const float oe = th / hn * ve;
  const size_t hidx = (size_t)(b * Hh + w) * Ll + l;
  const size_t oidx = hidx * DHh + lane;
  unsigned short hu, lu;
  if (mi == 0) {
    bsplit(oe, hu, lu);
    qhh[oidx] = hu; qhl[oidx] = lu;
    if (lane == 0) q2n[hidx] = th * th;
  } else if (mi == 1) {
    bsplit(oe, hu, lu);
    khh[oidx] = hu; khl[oidx] = lu;
    if (lane == 0) k2n[hidx] = th * th;
  } else {
    const float lam = 2.0f / fmaxf(1.0f - th * th, EPSf);
    vhh[oidx] = bhi(lam * oe);
    if (lane == 0) lam1[hidx] = lam - 1.0f;
  }
}

// ---------------------------------------------------------------------------
// Transpose lam*v per head: [k][d] -> [d][k] (bf16 hi only).
// ---------------------------------------------------------------------------
__global__ __launch_bounds__(256) void k_vt(const unsigned short* __restrict__ vh,
                                            unsigned short* __restrict__ th) {
  __shared__ __align__(16) unsigned short sh[64 * 72];
  const int t = threadIdx.x;
  const int bh = blockIdx.y, c = blockIdx.x;
  const size_t ibase = ((size_t)bh * Ll + c * 64) * DHh;
#pragma unroll
  for (int u = 0; u < 2; u++) {
    const int ch = t + u * 256, r = ch >> 3, f = ch & 7;
    *(short8*)&sh[r * 72 + f * 8] = *(const short8*)&vh[ibase + r * DHh + f * 8];
  }
  __syncthreads();
#pragma unroll
  for (int u = 0; u < 2; u++) {
    const int ch = t + u * 256, d = ch >> 3, kb = ch & 7;
    short8 oh;
#pragma unroll
    for (int i = 0; i < 8; i++) oh[i] = (short)sh[(kb * 8 + i) * 72 + d];
    const size_t ob = ((size_t)bh * DHh + d) * Ll + c * 64 + kb * 8;
    *(short8*)&th[ob] = oh;
  }
}

// ---------------------------------------------------------------------------
// Fused attention, SINGLE pass, double-buffered LDS, XCD-chunked block
// swizzle: the 16 q-tile blocks of one head land on ONE XCD, so each
// head's K/V is fetched into one L2 instead of all 8 (FETCH ~8x lower).
// Score via 1-t^2 identity; PV uses V hi only; bf16(e) -> attn row first
// half; k_norm expands+normalizes.
// ---------------------------------------------------------------------------
__global__ __launch_bounds__(256) void k_attn1(
    const unsigned short* __restrict__ qhh, const unsigned short* __restrict__ qhl,
    const unsigned short* __restrict__ khh, const unsigned short* __restrict__ khl,
    const unsigned short* __restrict__ vth,
    const float* __restrict__ q2n, const float* __restrict__ k2n,
    const float* __restrict__ lam1, const float* __restrict__ scale_p,
    float* __restrict__ attn, float* __restrict__ rowsum,
    float* __restrict__ yh) {
  __shared__ __align__(16) unsigned short kldsh[2][32 * 72];
  __shared__ __align__(16) unsigned short kldsl[2][32 * 72];
  __shared__ __align__(16) unsigned short vldsh[2][64 * 36];
  __shared__ __align__(16) unsigned short wlds[4][16 * 36];
  __shared__ __align__(16) float k2s[2][32];
  __shared__ __align__(16) float l1s[2][32];
  __shared__ __align__(16) float ik2s[2][32];
  __shared__ float dred[4][16];
  const int t = threadIdx.x, l = t & 63, w = t >> 6;
  const int lr = l & 15, lg = l >> 4;
  // XCD swizzle: 1536 wgs, 192 per XCD; work/16 = head, work%16 = q-tile.
  const int lin = blockIdx.y * 16 + blockIdx.x;
  const int work = (lin & 7) * 192 + (lin >> 3);
  const int bh = work >> 4, q0 = (work & 15) * 64;
  const size_t hbase = (size_t)bh * Ll;
  const float scale = scale_p[0];
  const bool sone = (scale == 1.0f);

  short8 aqh[2], aql[2];
#pragma unroll
  for (int s = 0; s < 2; s++) {
    const size_t off = (hbase + q0 + w * 16 + lr) * (size_t)DHh + s * 32 + lg * 8;
    aqh[s] = *(const short8*)&qhh[off];
    aql[s] = *(const short8*)&qhl[off];
  }
  const float q2v = q2n[hbase + q0 + w * 16 + lr];

  const int kr = t >> 3, kf = t & 7;
  const int vd = t >> 2, vf = t & 3;

  float rs = 0.0f, dacc = 0.0f;
  f32x4 pv[4] = {};

  short8 pkh, pkl, pvh;
  float k2r = 0.0f, l1r = 0.0f;
  auto load_chunk = [&](int c) {
    const size_t kg = (hbase + c * 32 + kr) * (size_t)DHh + kf * 8;
    pkh = *(const short8*)&khh[kg];
    pkl = *(const short8*)&khl[kg];
    const size_t vg = ((size_t)bh * DHh + vd) * (size_t)Ll + c * 32 + vf * 8;
    pvh = *(const short8*)&vth[vg];
    if (t < 32) {
      k2r = k2n[hbase + c * 32 + t];
      l1r = lam1[hbase + c * 32 + t];
    }
  };
  load_chunk(0);

  for (int c = 0; c < 32; c++) {
    const int pb = c & 1;
    *(short8*)&kldsh[pb][kr * 72 + kf * 8] = pkh;
    *(short8*)&kldsl[pb][kr * 72 + kf * 8] = pkl;
    *(short8*)&vldsh[pb][vd * 36 + vf * 8] = pvh;
    if (t < 32) {
      k2s[pb][t] = k2r;
      l1s[pb][t] = l1r;
      ik2s[pb][t] = __builtin_amdgcn_rcpf(1.0f - k2r);
    }
    if (c + 1 < 32) load_chunk(c + 1);  // prefetch c+1 (regs only)
    __syncthreads();  // writes visible; prior reads of buf pb (c-2) done

#pragma unroll
    for (int j = 0; j < 2; j++) {
      f32x4 acc = {};
#pragma unroll
      for (int s = 0; s < 2; s++) {
        const int ko = (j * 16 + lr) * 72 + s * 32 + lg * 8;
        const short8 kfh = *(const short8*)&kldsh[pb][ko];
        const short8 kfl = *(const short8*)&kldsl[pb][ko];
        acc = __builtin_amdgcn_mfma_f32_16x16x32_bf16(kfh, aqh[s], acc, 0, 0, 0);
        acc = __builtin_amdgcn_mfma_f32_16x16x32_bf16(kfh, aql[s], acc, 0, 0, 0);
        acc = __builtin_amdgcn_mfma_f32_16x16x32_bf16(kfl, aqh[s], acc, 0, 0, 0);
      }
      const float4 k2q = *(const float4*)&k2s[pb][j * 16 + lg * 4];
      const float4 l1q = *(const float4*)&l1s[pb][j * 16 + lg * 4];
      const float4 ikq = *(const float4*)&ik2s[pb][j * 16 + lg * 4];
      const float kq[4] = {k2q.x, k2q.y, k2q.z, k2q.w};
      const float lq[4] = {l1q.x, l1q.y, l1q.z, l1q.w};
      const float iq[4] = {ikq.x, ikq.y, ikq.z, ikq.w};
      short4v wv;
#pragma unroll
      for (int r = 0; r < 4; r++) {
        const float qk2 = acc[r] + acc[r];
        const float d = fmaxf(q2v + kq[r] - qk2, 0.0f);
        const float dn = fmaf(q2v, kq[r], 1.0f) - qk2;  // > 0.5 here
        const float m_ = fmaxf(d * dn, 1e-30f);
        const float s_ = m_ * __builtin_amdgcn_rsqf(m_);  // sqrt(d*dn)
        float e = (dn + d - s_ - s_) * iq[r];  // p*(1-q2) >= 0
        if (!sone) e = expf(scale * logf(fmaxf(e, 1e-30f)));
        rs += e;
        __hip_bfloat16 eb = __float2bfloat16(e);
        wv[r] = *(short*)&eb;
        dacc += __bfloat162float(eb) * lq[r];  // den from SAME rounded w
      }
      *(short4v*)&wlds[w][lr * 36 + j * 16 + lg * 4] = wv;
    }
    // PV: A = w (16q x 32k, bf16, wave-local), B = (lam v)^T hi [d][k].
    {
      const short8 wa = *(const short8*)&wlds[w][lr * 36 + lg * 8];
#pragma unroll
      for (int n = 0; n < 4; n++) {
        const short8 vbh8 = *(const short8*)&vldsh[pb][(n * 16 + lr) * 36 + lg * 8];
        pv[n] = __builtin_amdgcn_mfma_f32_16x16x32_bf16(wa, vbh8, pv[n], 0, 0, 0);
      }
    }
    // Coalesced bf16-e store: wave-local re-read of wlds, 16B per lane.
    {
      const int qy = l >> 2, cg = l & 3;
      const short8 ev = *(const short8*)&wlds[w][qy * 36 + cg * 8];
      unsigned short* eb =
          (unsigned short*)(attn + (hbase + q0 + w * 16 + qy) * (size_t)Ll);
      *(short8*)&eb[c * 32 + cg * 8] = ev;
    }
  }

  rs += __shfl_xor(rs, 16, 64);
  rs += __shfl_xor(rs, 32, 64);
  if (lg == 0) rowsum[hbase + q0 + w * 16 + lr] = rs;

  dacc += __shfl_xor(dacc, 16, 64);
  dacc += __shfl_xor(dacc, 32, 64);
  if (lg == 0) dred[w][lr] = dacc;

  const int b = bh / Hh, h = bh % Hh;
#pragma unroll
  for (int r = 0; r < 4; r++) {
    float den = dred[w][lg * 4 + r];
    if (fabsf(den) < 1e-10f) den = 1e-10f;
    const float dinv = 1.0f / den;
    float tm[4];
    float n2 = 0.0f;
#pragma unroll
    for (int n = 0; n < 4; n++) {
      tm[n] = pv[n][r] * dinv;
      n2 += tm[n] * tm[n];
    }
    n2 += __shfl_xor(n2, 1, 64);
    n2 += __shfl_xor(n2, 2, 64);
    n2 += __shfl_xor(n2, 4, 64);
    n2 += __shfl_xor(n2, 8, 64);
    const float nn = sqrtf(fmaxf(n2, EPSf * EPSf));
    const float nc = fminf(nn, MAXN);
    const float pn = nc / (1.0f + sqrtf(fmaxf(1.0f - nc * nc, 0.0f)));
    const float f = pn / nn * fminf(1.0f, MAXN / fmaxf(pn, EPSf));
    const int ql = q0 + w * 16 + lg * 4 + r;
#pragma unroll
    for (int n = 0; n < 4; n++)
      yh[(((size_t)(b * Ll + ql)) * Hh + h) * DHh + n * 16 + lr] = f * tm[n];
  }
}

// ---------------------------------------------------------------------------
// Normalize + expand: one row per block. Row's bf16 e values occupy the
// first 2 KB of the 4 KB fp32 row; read all (registers), sync, write fp32.
// ---------------------------------------------------------------------------
__global__ __launch_bounds__(256) void k_norm(float* __restrict__ attn,
                                              const float* __restrict__ rowsum) {
  const int row = blockIdx.x;
  const float rinv = 1.0f / rowsum[row];
  float* prow = attn + (size_t)row * Ll;
  const ushort4 u4 = ((const ushort4*)prow)[threadIdx.x];  // 4 bf16 e
  __syncthreads();  // all reads done before in-place expansion writes
  float4 v;
  v.x = bf2f(u4.x) * rinv;
  v.y = bf2f(u4.y) * rinv;
  v.z = bf2f(u4.z) * rinv;
  v.w = bf2f(u4.w) * rinv;
  ((float4*)prow)[threadIdx.x] = v;
}

// ---------------------------------------------------------------------------
// beta_concat: per-head logmap0 / BETA_RATIO, then expmap0 over full D.
// Also emits the bf16 (hi-only) copy of yc for the projection GEMM.
// ---------------------------------------------------------------------------
__global__ __launch_bounds__(768) void k_concat(
    const float* __restrict__ yh, float* __restrict__ yc,
    unsigned short* __restrict__ ychi, float beta_ratio) {
  const int t = threadIdx.x;
  const int row = blockIdx.x;
  const int w = t >> 6, lane = t & 63;
  __shared__ float red[12];
  const float ye = yh[(size_t)row * Dd + t];
  const float hs = wred64(ye * ye);
  const float hn = sqrtf(fmaxf(hs, EPSf * EPSf));
  const float cc = artanh_(fminf(hn, MAXN)) / hn / beta_ratio;
  const float ve = cc * ye;
  const float s = wred64(ve * ve);
  if (lane == 0) red[w] = s;
  __syncthreads();
  float n2 = 0.0f;
#pragma unroll
  for (int i = 0; i < 12; i++) n2 += red[i];
  const float n = sqrtf(fmaxf(n2, EPSf * EPSf));
  const float f = tanhf(n) / n;
  const float o = f * ve;
  yc[(size_t)row * Dd + t] = o;
  ychi[(size_t)row * Dd + t] = bhi(o);
}

// ---------------------------------------------------------------------------
// Final: mobius_matvec scaling (project), mobius_add with bias, project.
// ---------------------------------------------------------------------------
__global__ __launch_bounds__(768) void k_final(
    const float* __restrict__ yc, const float* __restrict__ mp,
    const float* __restrict__ bp, float* __restrict__ out) {
  const int t = threadIdx.x;
  const int row = blockIdx.x;
  const int w = t >> 6, lane = t & 63;
  __shared__ float red[12];
  auto blockSum = [&](float v) -> float {
    __syncthreads();
    const float s = wred64(v);
    if (lane == 0) red[w] = s;
    __syncthreads();
    float tot = 0.0f;
#pragma unroll
    for (int i = 0; i < 12; i++) tot += red[i];
    return tot;
  };
  const float xe = yc[(size_t)row * Dd + t];
  const float me = mp[(size_t)row * Dd + t];
  const float be = bp[t];
  const float xn2 = blockSum(xe * xe);
  const float xn = sqrtf(fmaxf(xn2, EPSf * EPSf));
  const float arx = artanh_(fminf(xn, MAXN));
  const float mn2 = blockSum(me * me);
  const float mxn = sqrtf(fmaxf(mn2, EPSf * EPSf));
  const float pn = tanhf(mxn / xn * arx);
  const float c1 = pn / mxn * fminf(1.0f, MAXN / fmaxf(pn, EPSf));
  const float mme = c1 * me;
  const float x2 = blockSum(mme * mme);
  const float y2 = blockSum(be * be);
  const float xy = blockSum(mme * be);
  const float nume = (1.0f + 2.0f * xy + y2) * mme + (1.0f - x2) * be;
  const float den = fmaxf(1.0f + 2.0f * xy + x2 * y2, EPSf);
  const float re = nume / den;
  const float rn2 = blockSum(re * re);
  const float rn = sqrtf(fmaxf(rn2, EPSf * EPSf));
  const float f = fminf(1.0f, MAXN / rn);
  out[(size_t)row * Dd + t] = f * re;
}

}  // namespace

extern "C" void kernel_launch(void* const* d_in, const int* in_sizes, int n_in,
                              void* d_out, int out_size, void* d_ws,
                              size_t ws_size, hipStream_t stream) {
  const float* x = (const float*)d_in[0];
  const float* Wq = (const float*)d_in[1];
  const float* Wk = (const float*)d_in[2];
  const float* Wv = (const float*)d_in[3];
  const float* Wp = (const float*)d_in[4];
  const float* bp = (const float*)d_in[5];
  const float* scale = (const float*)d_in[6];

  float* out = (float*)d_out;
  float* y_out = out;                        // (B,L,D)
  float* attn = out + (size_t)Bb * Ll * Dd;  // (B,H,L,L)

  const size_t NH = (size_t)Bb * Hh * Ll;  // 98304
  const size_t RD = (size_t)Bb * Ll * Dd;  // 6291456

  unsigned short* u = (unsigned short*)d_ws;
  unsigned short* qhh = u;
  unsigned short* qhl = u + RD;
  unsigned short* khh = u + 2 * RD;
  unsigned short* khl = u + 3 * RD;
  unsigned short* vth = u + 4 * RD;
  unsigned short* vhh = u + 6 * RD;  // dead after k_vt
  unsigned short* whi = u + 8 * RD;  // 4*DD ushorts (hi only)
  float* fb = (float*)(whi + 4 * (size_t)DDm);
  float* q2n = fb;
  float* k2n = fb + NH;
  float* lam1 = fb + 2 * NH;
  float* rowsum = fb + 3 * NH;
  float* xn2a = fb + 4 * NH;  // 8192 floats
  // overlays (dead-region reuse after k_attn1):
  float* yh = (float*)(u + 6 * RD);   // RD floats over vhh region
  float* yc = (float*)u;              // RD floats over qhh/qhl
  unsigned short* ychi = u + 2 * RD;  // over khh
  float* mp = (float*)(u + 4 * RD);   // RD floats over vth region

  // GEMM outputs + bf16 x staged in the not-yet-written attn region.
  float* mq = attn;
  float* mk = attn + RD;
  float* mv = attn + 2 * RD;
  unsigned short* xhi = (unsigned short*)(attn + 3 * RD);

  const double br =
      exp(lgamma(DHh / 2.0) + lgamma(0.5) - lgamma(DHh / 2.0 + 0.5) -
          (lgamma(Dd / 2.0) + lgamma(0.5) - lgamma(Dd / 2.0 + 0.5)));
  const float beta_ratio = (float)br;

  (void)in_sizes; (void)n_in; (void)out_size; (void)ws_size;

  k_cvtx<<<dim3(Bb * Ll), dim3(768), 0, stream>>>(x, xhi, xn2a);
  k_cvt4<<<dim3(DDm / 4 / 256, 1, 4), dim3(256), 0, stream>>>(Wq, Wk, Wv, Wp,
                                                              whi);

  k_gemm_bf16h<<<dim3(Dd / 128, (Bb * Ll) / 128, 3), dim3(256), 0, stream>>>(
      xhi, whi, mq);

  k_qkvt3<<<dim3(Bb * Ll, 3), dim3(768), 0, stream>>>(
      xn2a, mq, mk, mv, qhh, qhl, khh, khl, vhh, q2n, k2n, lam1, beta_ratio);

  k_vt<<<dim3(16, Bb * Hh), dim3(256), 0, stream>>>(vhh, vth);

  k_attn1<<<dim3(16, Bb * Hh), dim3(256), 0, stream>>>(
      qhh, qhl, khh, khl, vth, q2n, k2n, lam1, scale, attn, rowsum, yh);

  k_norm<<<dim3((int)NH), dim3(256), 0, stream>>>(attn, rowsum);

  k_concat<<<dim3(Bb * Ll), dim3(768), 0, stream>>>(yh, yc, ychi, beta_ratio);

  k_gemm_bf16h<<<dim3(Dd / 128, (Bb * Ll) / 128, 1), dim3(256), 0, stream>>>(
      ychi, whi + 3 * (size_t)DDm, mp);

  k_final<<<dim3(Bb * Ll), dim3(768), 0, stream>>>(yc, mp, bp, y_out);
}

// Round 17
// 579.143 us; speedup vs baseline: 1.1075x; 1.0257x over previous
//
#include <hip/hip_runtime.h>
#include <hip/hip_bf16.h>
#include <math.h>

namespace {

constexpr int Bb = 8, Ll = 1024, Dd = 768, Hh = 12, DHh = 64;
constexpr int DDm = Dd * Dd;
constexpr float MAXN = 1.0f - 1e-5f;
constexpr float EPSf = 1e-15f;

typedef __attribute__((ext_vector_type(8))) short short8;
typedef __attribute__((ext_vector_type(4))) short short4v;
typedef __attribute__((ext_vector_type(4))) float f32x4;

__device__ __forceinline__ float wred64(float v) {
#pragma unroll
  for (int m = 32; m >= 1; m >>= 1) v += __shfl_xor(v, m, 64);
  return v;
}

__device__ __forceinline__ float artanh_(float x) {
  return 0.5f * logf((1.0f + x) / (1.0f - x));
}

__device__ __forceinline__ unsigned short bhi(float x) {
  __hip_bfloat16 hb = __float2bfloat16(x);
  return *(unsigned short*)&hb;
}

__device__ __forceinline__ float bf2f(unsigned short u) {
  union { unsigned int i; float f; } cv;
  cv.i = ((unsigned int)u) << 16;
  return cv.f;
}

// Async global->LDS 16B DMA (gfx950). LDS dest must be wave-uniform base +
// lane*16 (linear in lane order) — swizzling is done on the SOURCE address.
__device__ __forceinline__ void gll16(const unsigned short* g,
                                      unsigned short* l) {
  __builtin_amdgcn_global_load_lds(
      (const __attribute__((address_space(1))) void*)g,
      (__attribute__((address_space(3))) void*)l, 16, 0, 0);
}

// ---------------------------------------------------------------------------
// x -> bf16 (hi only, for GEMM A) + per-row squared norm.
// ---------------------------------------------------------------------------
__global__ __launch_bounds__(768) void k_cvtx(const float* __restrict__ x,
                                              unsigned short* __restrict__ hi,
                                              float* __restrict__ xn2a) {
  const int t = threadIdx.x;
  const int row = blockIdx.x;
  const int w = t >> 6, lane = t & 63;
  __shared__ float red[12];
  const float xe = x[(size_t)row * Dd + t];
  hi[(size_t)row * Dd + t] = bhi(xe);
  const float s = wred64(xe * xe);
  if (lane == 0) red[w] = s;
  __syncthreads();
  if (t == 0) {
    float tot = 0.0f;
#pragma unroll
    for (int i = 0; i < 12; i++) tot += red[i];
    xn2a[row] = tot;
  }
}

// 4 weight matrices -> bf16 hi in one launch (blockIdx.z selects source).
__global__ __launch_bounds__(256) void k_cvt4(
    const float* __restrict__ w0, const float* __restrict__ w1,
    const float* __restrict__ w2, const float* __restrict__ w3,
    unsigned short* __restrict__ hi) {
  const int z = blockIdx.z;
  const float* in = (z == 0) ? w0 : (z == 1) ? w1 : (z == 2) ? w2 : w3;
  const int i = blockIdx.x * 256 + threadIdx.x;
  if (i >= DDm / 4) return;
  float4 v = ((const float4*)in)[i];
  ((ushort4*)(hi + (size_t)z * DDm))[i] =
      make_ushort4(bhi(v.x), bhi(v.y), bhi(v.z), bhi(v.w));
}

// ---------------------------------------------------------------------------
// Pure-bf16 MFMA GEMM: C = A @ W^T. m97-shape, XCD-chunked block swizzle.
// ---------------------------------------------------------------------------
__global__ __launch_bounds__(256) void k_gemm_bf16h(
    const unsigned short* __restrict__ Ahi,
    const unsigned short* __restrict__ Whi, float* __restrict__ C) {
  constexpr int K = Dd, N = Dd;
  const int gxy = gridDim.x * gridDim.y;
  const int nwg = gxy * gridDim.z;
  const int lin = (blockIdx.z * gridDim.y + blockIdx.y) * gridDim.x + blockIdx.x;
  const int work = (lin & 7) * (nwg >> 3) + (lin >> 3);
  const int z = work / gxy;
  const int rem = work - z * gxy;
  const int by = rem / gridDim.x;
  const int bx = rem - by * gridDim.x;

  const unsigned short* Bh = Whi + (size_t)z * DDm;
  float* Cz = C + (size_t)z * 8192 * N;
  __shared__ __align__(16) unsigned short sAh[128 * 32];
  __shared__ __align__(16) unsigned short sBh[128 * 32];
  const int t = threadIdx.x;
  const int l = t & 63, wid = t >> 6;
  const int wr = wid >> 1, wc = wid & 1;
  const int m0 = by * 128, n0 = bx * 128;

  const int r0 = t >> 2;
  const int kfs = ((t & 3) ^ ((r0 >> 1) & 3)) << 3;
  const size_t ga0 = (size_t)(m0 + r0) * K + kfs;
  const size_t ga1 = (size_t)(m0 + r0 + 64) * K + kfs;
  const size_t gb0 = (size_t)(n0 + r0) * K + kfs;
  const size_t gb1 = (size_t)(n0 + r0 + 64) * K + kfs;
  unsigned short* dA0 = &sAh[t * 8];
  unsigned short* dA1 = &sAh[(t + 256) * 8];
  unsigned short* dB0 = &sBh[t * 8];
  unsigned short* dB1 = &sBh[(t + 256) * 8];

  const int lar = l & 15, lkf = l >> 4;

  f32x4 acc[4][4] = {};

  for (int k0 = 0; k0 < K; k0 += 32) {
    __syncthreads();  // prior iteration's LDS reads complete
    gll16(&Ahi[ga0 + k0], dA0);
    gll16(&Ahi[ga1 + k0], dA1);
    gll16(&Bh[gb0 + k0], dB0);
    gll16(&Bh[gb1 + k0], dB1);
    __syncthreads();  // vmcnt drained -> staging visible

    short8 ah[4], bh[4];
#pragma unroll
    for (int f = 0; f < 4; f++) {
      const int ra = wr * 64 + f * 16 + lar;
      const int ia = ra * 32 + ((lkf ^ ((ra >> 1) & 3)) << 3);
      ah[f] = *(const short8*)&sAh[ia];
      const int rb = wc * 64 + f * 16 + lar;
      const int ib = rb * 32 + ((lkf ^ ((rb >> 1) & 3)) << 3);
      bh[f] = *(const short8*)&sBh[ib];
    }
#pragma unroll
    for (int i = 0; i < 4; i++)
#pragma unroll
      for (int j = 0; j < 4; j++)
        acc[i][j] = __builtin_amdgcn_mfma_f32_16x16x32_bf16(ah[i], bh[j],
                                                            acc[i][j], 0, 0, 0);
  }

#pragma unroll
  for (int i = 0; i < 4; i++)
#pragma unroll
    for (int j = 0; j < 4; j++) {
      const int row = m0 + wr * 64 + i * 16 + (l >> 4) * 4;
      const int col = n0 + wc * 64 + j * 16 + (l & 15);
      const f32x4 v = acc[i][j];
#pragma unroll
      for (int q = 0; q < 4; q++) Cz[(size_t)(row + q) * N + col] = v[q];
    }
}

// ---------------------------------------------------------------------------
// Per-row transform, one (row, mi) per block. Emits q/k/(lam*v) as bf16
// HI ONLY + per-head stats (q2/k2 exact fp32).
// ---------------------------------------------------------------------------
__global__ __launch_bounds__(768) void k_qkvt3(
    const float* __restrict__ xn2a,
    const float* __restrict__ mq, const float* __restrict__ mk,
    const float* __restrict__ mv,
    unsigned short* __restrict__ qhh, unsigned short* __restrict__ khh,
    unsigned short* __restrict__ vhh,
    float* __restrict__ q2n, float* __restrict__ k2n,
    float* __restrict__ lam1, float beta_ratio) {
  const int t = threadIdx.x;
  const int row = blockIdx.x;  // b*L + l
  const int mi = blockIdx.y;
  const int b = row >> 10, l = row & 1023;
  const int w = t >> 6, lane = t & 63;
  __shared__ float red[12];

  const float* m = (mi == 0) ? mq : (mi == 1) ? mk : mv;
  const float me = m[(size_t)row * Dd + t];
  const float s2 = wred64(me * me);
  if (lane == 0) red[w] = s2;
  __syncthreads();
  float mn2 = 0.0f;
#pragma unroll
  for (int i = 0; i < 12; i++) mn2 += red[i];

  const float xn = sqrtf(fmaxf(xn2a[row], EPSf * EPSf));
  const float arx = artanh_(fminf(xn, MAXN));

  const float mxn = sqrtf(fmaxf(mn2, EPSf * EPSf));
  const float pn = tanhf(mxn / xn * arx);
  const float c1 = pn / mxn * fminf(1.0f, MAXN / fmaxf(pn, EPSf));
  const float nn = fmaxf(fminf(pn, MAXN), EPSf);
  const float c2 = artanh_(nn) / nn;
  const float ve = c2 * c1 * me * beta_ratio;
  const float hs = wred64(ve * ve);
  const float hn = sqrtf(fmaxf(hs, EPSf * EPSf));
  const float th = tanhf(hn);
  const float oe = th / hn * ve;
  const size_t hidx = (size_t)(b * Hh + w) * Ll + l;
  const size_t oidx = hidx * DHh + lane;
  if (mi == 0) {
    qhh[oidx] = bhi(oe);
    if (lane == 0) q2n[hidx] = th * th;
  } else if (mi == 1) {
    khh[oidx] = bhi(oe);
    if (lane == 0) k2n[hidx] = th * th;
  } else {
    const float lam = 2.0f / fmaxf(1.0f - th * th, EPSf);
    vhh[oidx] = bhi(lam * oe);
    if (lane == 0) lam1[hidx] = lam - 1.0f;
  }
}

// ---------------------------------------------------------------------------
// Transpose lam*v per head: [k][d] -> [d][k] (bf16 hi only).
// ---------------------------------------------------------------------------
__global__ __launch_bounds__(256) void k_vt(const unsigned short* __restrict__ vh,
                                            unsigned short* __restrict__ th) {
  __shared__ __align__(16) unsigned short sh[64 * 72];
  const int t = threadIdx.x;
  const int bh = blockIdx.y, c = blockIdx.x;
  const size_t ibase = ((size_t)bh * Ll + c * 64) * DHh;
#pragma unroll
  for (int u = 0; u < 2; u++) {
    const int ch = t + u * 256, r = ch >> 3, f = ch & 7;
    *(short8*)&sh[r * 72 + f * 8] = *(const short8*)&vh[ibase + r * DHh + f * 8];
  }
  __syncthreads();
#pragma unroll
  for (int u = 0; u < 2; u++) {
    const int ch = t + u * 256, d = ch >> 3, kb = ch & 7;
    short8 oh;
#pragma unroll
    for (int i = 0; i < 8; i++) oh[i] = (short)sh[(kb * 8 + i) * 72 + d];
    const size_t ob = ((size_t)bh * DHh + d) * Ll + c * 64 + kb * 8;
    *(short8*)&th[ob] = oh;
  }
}

// ---------------------------------------------------------------------------
// Fused attention, SINGLE pass, double-buffered LDS, XCD-chunked swizzle.
// Q/K/V all bf16 hi-only: QK^T is ONE MFMA per (j,s) (score e=(sqrt(dn)-
// sqrt(d))^2 * ik2 is a perfect square -> robust to rounding). PV V hi.
// bf16(e) -> attn row first half; k_norm expands+normalizes.
// ---------------------------------------------------------------------------
__global__ __launch_bounds__(256) void k_attn1(
    const unsigned short* __restrict__ qhh, const unsigned short* __restrict__ khh,
    const unsigned short* __restrict__ vth,
    const float* __restrict__ q2n, const float* __restrict__ k2n,
    const float* __restrict__ lam1, const float* __restrict__ scale_p,
    float* __restrict__ attn, float* __restrict__ rowsum,
    float* __restrict__ yh) {
  __shared__ __align__(16) unsigned short kldsh[2][32 * 72];
  __shared__ __align__(16) unsigned short vldsh[2][64 * 36];
  __shared__ __align__(16) unsigned short wlds[4][16 * 36];
  __shared__ __align__(16) float k2s[2][32];
  __shared__ __align__(16) float l1s[2][32];
  __shared__ __align__(16) float ik2s[2][32];
  __shared__ float dred[4][16];
  const int t = threadIdx.x, l = t & 63, w = t >> 6;
  const int lr = l & 15, lg = l >> 4;
  // XCD swizzle: 1536 wgs, 192 per XCD; work/16 = head, work%16 = q-tile.
  const int lin = blockIdx.y * 16 + blockIdx.x;
  const int work = (lin & 7) * 192 + (lin >> 3);
  const int bh = work >> 4, q0 = (work & 15) * 64;
  const size_t hbase = (size_t)bh * Ll;
  const float scale = scale_p[0];
  const bool sone = (scale == 1.0f);

  short8 aqh[2];
#pragma unroll
  for (int s = 0; s < 2; s++) {
    const size_t off = (hbase + q0 + w * 16 + lr) * (size_t)DHh + s * 32 + lg * 8;
    aqh[s] = *(const short8*)&qhh[off];
  }
  const float q2v = q2n[hbase + q0 + w * 16 + lr];

  const int kr = t >> 3, kf = t & 7;
  const int vd = t >> 2, vf = t & 3;

  float rs = 0.0f, dacc = 0.0f;
  f32x4 pv[4] = {};

  short8 pkh, pvh;
  float k2r = 0.0f, l1r = 0.0f;
  auto load_chunk = [&](int c) {
    const size_t kg = (hbase + c * 32 + kr) * (size_t)DHh + kf * 8;
    pkh = *(const short8*)&khh[kg];
    const size_t vg = ((size_t)bh * DHh + vd) * (size_t)Ll + c * 32 + vf * 8;
    pvh = *(const short8*)&vth[vg];
    if (t < 32) {
      k2r = k2n[hbase + c * 32 + t];
      l1r = lam1[hbase + c * 32 + t];
    }
  };
  load_chunk(0);

  for (int c = 0; c < 32; c++) {
    const int pb = c & 1;
    *(short8*)&kldsh[pb][kr * 72 + kf * 8] = pkh;
    *(short8*)&vldsh[pb][vd * 36 + vf * 8] = pvh;
    if (t < 32) {
      k2s[pb][t] = k2r;
      l1s[pb][t] = l1r;
      ik2s[pb][t] = __builtin_amdgcn_rcpf(1.0f - k2r);
    }
    if (c + 1 < 32) load_chunk(c + 1);  // prefetch c+1 (regs only)
    __syncthreads();  // writes visible; prior reads of buf pb (c-2) done

#pragma unroll
    for (int j = 0; j < 2; j++) {
      f32x4 acc = {};
#pragma unroll
      for (int s = 0; s < 2; s++) {
        const int ko = (j * 16 + lr) * 72 + s * 32 + lg * 8;
        const short8 kfh = *(const short8*)&kldsh[pb][ko];
        acc = __builtin_amdgcn_mfma_f32_16x16x32_bf16(kfh, aqh[s], acc, 0, 0, 0);
      }
      const float4 k2q = *(const float4*)&k2s[pb][j * 16 + lg * 4];
      const float4 l1q = *(const float4*)&l1s[pb][j * 16 + lg * 4];
      const float4 ikq = *(const float4*)&ik2s[pb][j * 16 + lg * 4];
      const float kq[4] = {k2q.x, k2q.y, k2q.z, k2q.w};
      const float lq[4] = {l1q.x, l1q.y, l1q.z, l1q.w};
      const float iq[4] = {ikq.x, ikq.y, ikq.z, ikq.w};
      short4v wv;
#pragma unroll
      for (int r = 0; r < 4; r++) {
        const float qk2 = acc[r] + acc[r];
        const float d = fmaxf(q2v + kq[r] - qk2, 0.0f);
        const float dn = fmaf(q2v, kq[r], 1.0f) - qk2;  // > 0.4 here
        const float m_ = fmaxf(d * dn, 1e-30f);
        const float s_ = m_ * __builtin_amdgcn_rsqf(m_);  // sqrt(d*dn)
        float e = (dn + d - s_ - s_) * iq[r];  // (sqrt(dn)-sqrt(d))^2 >= 0
        if (!sone) e = expf(scale * logf(fmaxf(e, 1e-30f)));
        rs += e;
        __hip_bfloat16 eb = __float2bfloat16(e);
        wv[r] = *(short*)&eb;
        dacc += bf2f(*(unsigned short*)&eb) * lq[r];  // den from rounded w
      }
      *(short4v*)&wlds[w][lr * 36 + j * 16 + lg * 4] = wv;
    }
    // PV: A = w (16q x 32k, bf16, wave-local), B = (lam v)^T hi [d][k].
    {
      const short8 wa = *(const short8*)&wlds[w][lr * 36 + lg * 8];
#pragma unroll
      for (int n = 0; n < 4; n++) {
        const short8 vbh8 = *(const short8*)&vldsh[pb][(n * 16 + lr) * 36 + lg * 8];
        pv[n] = __builtin_amdgcn_mfma_f32_16x16x32_bf16(wa, vbh8, pv[n], 0, 0, 0);
      }
    }
    // Coalesced bf16-e store: wave-local re-read of wlds, 16B per lane.
    {
      const int qy = l >> 2, cg = l & 3;
      const short8 ev = *(const short8*)&wlds[w][qy * 36 + cg * 8];
      unsigned short* eb =
          (unsigned short*)(attn + (hbase + q0 + w * 16 + qy) * (size_t)Ll);
      *(short8*)&eb[c * 32 + cg * 8] = ev;
    }
  }

  rs += __shfl_xor(rs, 16, 64);
  rs += __shfl_xor(rs, 32, 64);
  if (lg == 0) rowsum[hbase + q0 + w * 16 + lr] = rs;

  dacc += __shfl_xor(dacc, 16, 64);
  dacc += __shfl_xor(dacc, 32, 64);
  if (lg == 0) dred[w][lr] = dacc;

  const int b = bh / Hh, h = bh % Hh;
#pragma unroll
  for (int r = 0; r < 4; r++) {
    float den = dred[w][lg * 4 + r];
    if (fabsf(den) < 1e-10f) den = 1e-10f;
    const float dinv = 1.0f / den;
    float tm[4];
    float n2 = 0.0f;
#pragma unroll
    for (int n = 0; n < 4; n++) {
      tm[n] = pv[n][r] * dinv;
      n2 += tm[n] * tm[n];
    }
    n2 += __shfl_xor(n2, 1, 64);
    n2 += __shfl_xor(n2, 2, 64);
    n2 += __shfl_xor(n2, 4, 64);
    n2 += __shfl_xor(n2, 8, 64);
    const float nn = sqrtf(fmaxf(n2, EPSf * EPSf));
    const float nc = fminf(nn, MAXN);
    const float pn = nc / (1.0f + sqrtf(fmaxf(1.0f - nc * nc, 0.0f)));
    const float f = pn / nn * fminf(1.0f, MAXN / fmaxf(pn, EPSf));
    const int ql = q0 + w * 16 + lg * 4 + r;
#pragma unroll
    for (int n = 0; n < 4; n++)
      yh[(((size_t)(b * Ll + ql)) * Hh + h) * DHh + n * 16 + lr] = f * tm[n];
  }
}

// ---------------------------------------------------------------------------
// Normalize + expand: one row per block. Row's bf16 e values occupy the
// first 2 KB of the 4 KB fp32 row; read all (registers), sync, write fp32.
// ---------------------------------------------------------------------------
__global__ __launch_bounds__(256) void k_norm(float* __restrict__ attn,
                                              const float* __restrict__ rowsum) {
  const int row = blockIdx.x;
  const float rinv = 1.0f / rowsum[row];
  float* prow = attn + (size_t)row * Ll;
  const ushort4 u4 = ((const ushort4*)prow)[threadIdx.x];  // 4 bf16 e
  __syncthreads();  // all reads done before in-place expansion writes
  float4 v;
  v.x = bf2f(u4.x) * rinv;
  v.y = bf2f(u4.y) * rinv;
  v.z = bf2f(u4.z) * rinv;
  v.w = bf2f(u4.w) * rinv;
  ((float4*)prow)[threadIdx.x] = v;
}

// ---------------------------------------------------------------------------
// beta_concat: per-head logmap0 / BETA_RATIO, then expmap0 over full D.
// Also emits the bf16 (hi-only) copy of yc for the projection GEMM.
// ---------------------------------------------------------------------------
__global__ __launch_bounds__(768) void k_concat(
    const float* __restrict__ yh, float* __restrict__ yc,
    unsigned short* __restrict__ ychi, float beta_ratio) {
  const int t = threadIdx.x;
  const int row = blockIdx.x;
  const int w = t >> 6, lane = t & 63;
  __shared__ float red[12];
  const float ye = yh[(size_t)row * Dd + t];
  const float hs = wred64(ye * ye);
  const float hn = sqrtf(fmaxf(hs, EPSf * EPSf));
  const float cc = artanh_(fminf(hn, MAXN)) / hn / beta_ratio;
  const float ve = cc * ye;
  const float s = wred64(ve * ve);
  if (lane == 0) red[w] = s;
  __syncthreads();
  float n2 = 0.0f;
#pragma unroll
  for (int i = 0; i < 12; i++) n2 += red[i];
  const float n = sqrtf(fmaxf(n2, EPSf * EPSf));
  const float f = tanhf(n) / n;
  const float o = f * ve;
  yc[(size_t)row * Dd + t] = o;
  ychi[(size_t)row * Dd + t] = bhi(o);
}

// ---------------------------------------------------------------------------
// Final: mobius_matvec scaling (project), mobius_add with bias, project.
// ---------------------------------------------------------------------------
__global__ __launch_bounds__(768) void k_final(
    const float* __restrict__ yc, const float* __restrict__ mp,
    const float* __restrict__ bp, float* __restrict__ out) {
  const int t = threadIdx.x;
  const int row = blockIdx.x;
  const int w = t >> 6, lane = t & 63;
  __shared__ float red[12];
  auto blockSum = [&](float v) -> float {
    __syncthreads();
    const float s = wred64(v);
    if (lane == 0) red[w] = s;
    __syncthreads();
    float tot = 0.0f;
#pragma unroll
    for (int i = 0; i < 12; i++) tot += red[i];
    return tot;
  };
  const float xe = yc[(size_t)row * Dd + t];
  const float me = mp[(size_t)row * Dd + t];
  const float be = bp[t];
  const float xn2 = blockSum(xe * xe);
  const float xn = sqrtf(fmaxf(xn2, EPSf * EPSf));
  const float arx = artanh_(fminf(xn, MAXN));
  const float mn2 = blockSum(me * me);
  const float mxn = sqrtf(fmaxf(mn2, EPSf * EPSf));
  const float pn = tanhf(mxn / xn * arx);
  const float c1 = pn / mxn * fminf(1.0f, MAXN / fmaxf(pn, EPSf));
  const float mme = c1 * me;
  const float x2 = blockSum(mme * mme);
  const float y2 = blockSum(be * be);
  const float xy = blockSum(mme * be);
  const float nume = (1.0f + 2.0f * xy + y2) * mme + (1.0f - x2) * be;
  const float den = fmaxf(1.0f + 2.0f * xy + x2 * y2, EPSf);
  const float re = nume / den;
  const float rn2 = blockSum(re * re);
  const float rn = sqrtf(fmaxf(rn2, EPSf * EPSf));
  const float f = fminf(1.0f, MAXN / rn);
  out[(size_t)row * Dd + t] = f * re;
}

}  // namespace

extern "C" void kernel_launch(void* const* d_in, const int* in_sizes, int n_in,
                              void* d_out, int out_size, void* d_ws,
                              size_t ws_size, hipStream_t stream) {
  const float* x = (const float*)d_in[0];
  const float* Wq = (const float*)d_in[1];
  const float* Wk = (const float*)d_in[2];
  const float* Wv = (const float*)d_in[3];
  const float* Wp = (const float*)d_in[4];
  const float* bp = (const float*)d_in[5];
  const float* scale = (const float*)d_in[6];

  float* out = (float*)d_out;
  float* y_out = out;                        // (B,L,D)
  float* attn = out + (size_t)Bb * Ll * Dd;  // (B,H,L,L)

  const size_t NH = (size_t)Bb * Hh * Ll;  // 98304
  const size_t RD = (size_t)Bb * Ll * Dd;  // 6291456

  unsigned short* u = (unsigned short*)d_ws;
  unsigned short* qhh = u;               // RD (dead after k_attn1)
  unsigned short* khh = u + RD;          // RD (dead after k_attn1)
  unsigned short* vth = u + 2 * RD;      // RD (dead after k_attn1)
  unsigned short* vhh = u + 3 * RD;      // RD (dead after k_vt)
  float* yh = (float*)(u + 4 * RD);      // RD floats (2 RD shorts)
  unsigned short* whi = u + 6 * RD;      // 4*DDm shorts
  float* fb = (float*)(whi + 4 * (size_t)DDm);
  float* q2n = fb;
  float* k2n = fb + NH;
  float* lam1 = fb + 2 * NH;
  float* rowsum = fb + 3 * NH;
  float* xn2a = fb + 4 * NH;  // 8192 floats
  // overlays for the tail (dead-region reuse):
  float* yc = (float*)u;              // RD floats over qhh/khh (post-attn1)
  unsigned short* ychi = u + 2 * RD;  // RD shorts over vth (post-attn1)
  float* mp = (float*)(u + 4 * RD);   // RD floats over yh (post-k_concat)

  // GEMM outputs + bf16 x staged in the not-yet-written attn region.
  float* mq = attn;
  float* mk = attn + RD;
  float* mv = attn + 2 * RD;
  unsigned short* xhi = (unsigned short*)(attn + 3 * RD);

  const double br =
      exp(lgamma(DHh / 2.0) + lgamma(0.5) - lgamma(DHh / 2.0 + 0.5) -
          (lgamma(Dd / 2.0) + lgamma(0.5) - lgamma(Dd / 2.0 + 0.5)));
  const float beta_ratio = (float)br;

  (void)in_sizes; (void)n_in; (void)out_size; (void)ws_size;

  k_cvtx<<<dim3(Bb * Ll), dim3(768), 0, stream>>>(x, xhi, xn2a);
  k_cvt4<<<dim3(DDm / 4 / 256, 1, 4), dim3(256), 0, stream>>>(Wq, Wk, Wv, Wp,
                                                              whi);

  k_gemm_bf16h<<<dim3(Dd / 128, (Bb * Ll) / 128, 3), dim3(256), 0, stream>>>(
      xhi, whi, mq);

  k_qkvt3<<<dim3(Bb * Ll, 3), dim3(768), 0, stream>>>(
      xn2a, mq, mk, mv, qhh, khh, vhh, q2n, k2n, lam1, beta_ratio);

  k_vt<<<dim3(16, Bb * Hh), dim3(256), 0, stream>>>(vhh, vth);

  k_attn1<<<dim3(16, Bb * Hh), dim3(256), 0, stream>>>(
      qhh, khh, vth, q2n, k2n, lam1, scale, attn, rowsum, yh);

  k_norm<<<dim3((int)NH), dim3(256), 0, stream>>>(attn, rowsum);

  k_concat<<<dim3(Bb * Ll), dim3(768), 0, stream>>>(yh, yc, ychi, beta_ratio);

  k_gemm_bf16h<<<dim3(Dd / 128, (Bb * Ll) / 128, 1), dim3(256), 0, stream>>>(
      ychi, whi + 3 * (size_t)DDm, mp);

  k_final<<<dim3(Bb * Ll), dim3(768), 0, stream>>>(yc, mp, bp, y_out);
}

// Round 18
// 562.308 us; speedup vs baseline: 1.1407x; 1.0299x over previous
//
#include <hip/hip_runtime.h>
#include <hip/hip_bf16.h>
#include <math.h>

namespace {

constexpr int Bb = 8, Ll = 1024, Dd = 768, Hh = 12, DHh = 64;
constexpr int DDm = Dd * Dd;
constexpr float MAXN = 1.0f - 1e-5f;
constexpr float EPSf = 1e-15f;

typedef __attribute__((ext_vector_type(8))) short short8;
typedef __attribute__((ext_vector_type(4))) short short4v;
typedef __attribute__((ext_vector_type(4))) float f32x4;

__device__ __forceinline__ float wred64(float v) {
#pragma unroll
  for (int m = 32; m >= 1; m >>= 1) v += __shfl_xor(v, m, 64);
  return v;
}

__device__ __forceinline__ float artanh_(float x) {
  return 0.5f * logf((1.0f + x) / (1.0f - x));
}

__device__ __forceinline__ unsigned short bhi(float x) {
  __hip_bfloat16 hb = __float2bfloat16(x);
  return *(unsigned short*)&hb;
}

__device__ __forceinline__ float bf2f(unsigned short u) {
  union { unsigned int i; float f; } cv;
  cv.i = ((unsigned int)u) << 16;
  return cv.f;
}

// Async global->LDS 16B DMA (gfx950). LDS dest must be wave-uniform base +
// lane*16 (linear in lane order) — swizzling is done on the SOURCE address.
__device__ __forceinline__ void gll16(const unsigned short* g,
                                      unsigned short* l) {
  __builtin_amdgcn_global_load_lds(
      (const __attribute__((address_space(1))) void*)g,
      (__attribute__((address_space(3))) void*)l, 16, 0, 0);
}

// ---------------------------------------------------------------------------
// x -> bf16 (hi only, for GEMM A) + per-row squared norm.
// ---------------------------------------------------------------------------
__global__ __launch_bounds__(768) void k_cvtx(const float* __restrict__ x,
                                              unsigned short* __restrict__ hi,
                                              float* __restrict__ xn2a) {
  const int t = threadIdx.x;
  const int row = blockIdx.x;
  const int w = t >> 6, lane = t & 63;
  __shared__ float red[12];
  const float xe = x[(size_t)row * Dd + t];
  hi[(size_t)row * Dd + t] = bhi(xe);
  const float s = wred64(xe * xe);
  if (lane == 0) red[w] = s;
  __syncthreads();
  if (t == 0) {
    float tot = 0.0f;
#pragma unroll
    for (int i = 0; i < 12; i++) tot += red[i];
    xn2a[row] = tot;
  }
}

// 4 weight matrices -> bf16 hi in one launch (blockIdx.z selects source).
__global__ __launch_bounds__(256) void k_cvt4(
    const float* __restrict__ w0, const float* __restrict__ w1,
    const float* __restrict__ w2, const float* __restrict__ w3,
    unsigned short* __restrict__ hi) {
  const int z = blockIdx.z;
  const float* in = (z == 0) ? w0 : (z == 1) ? w1 : (z == 2) ? w2 : w3;
  const int i = blockIdx.x * 256 + threadIdx.x;
  if (i >= DDm / 4) return;
  float4 v = ((const float4*)in)[i];
  ((ushort4*)(hi + (size_t)z * DDm))[i] =
      make_ushort4(bhi(v.x), bhi(v.y), bhi(v.z), bhi(v.w));
}

// ---------------------------------------------------------------------------
// Pure-bf16 MFMA GEMM: C = A @ W^T, bf16 OUTPUT (consumers re-round to bf16
// anyway; halves C traffic). m97-shape, XCD-chunked block swizzle.
// ---------------------------------------------------------------------------
__global__ __launch_bounds__(256) void k_gemm_bf16h(
    const unsigned short* __restrict__ Ahi,
    const unsigned short* __restrict__ Whi, unsigned short* __restrict__ C) {
  constexpr int K = Dd, N = Dd;
  const int gxy = gridDim.x * gridDim.y;
  const int nwg = gxy * gridDim.z;
  const int lin = (blockIdx.z * gridDim.y + blockIdx.y) * gridDim.x + blockIdx.x;
  const int work = (lin & 7) * (nwg >> 3) + (lin >> 3);
  const int z = work / gxy;
  const int rem = work - z * gxy;
  const int by = rem / gridDim.x;
  const int bx = rem - by * gridDim.x;

  const unsigned short* Bh = Whi + (size_t)z * DDm;
  unsigned short* Cz = C + (size_t)z * 8192 * N;
  __shared__ __align__(16) unsigned short sAh[128 * 32];
  __shared__ __align__(16) unsigned short sBh[128 * 32];
  const int t = threadIdx.x;
  const int l = t & 63, wid = t >> 6;
  const int wr = wid >> 1, wc = wid & 1;
  const int m0 = by * 128, n0 = bx * 128;

  const int r0 = t >> 2;
  const int kfs = ((t & 3) ^ ((r0 >> 1) & 3)) << 3;
  const size_t ga0 = (size_t)(m0 + r0) * K + kfs;
  const size_t ga1 = (size_t)(m0 + r0 + 64) * K + kfs;
  const size_t gb0 = (size_t)(n0 + r0) * K + kfs;
  const size_t gb1 = (size_t)(n0 + r0 + 64) * K + kfs;
  unsigned short* dA0 = &sAh[t * 8];
  unsigned short* dA1 = &sAh[(t + 256) * 8];
  unsigned short* dB0 = &sBh[t * 8];
  unsigned short* dB1 = &sBh[(t + 256) * 8];

  const int lar = l & 15, lkf = l >> 4;

  f32x4 acc[4][4] = {};

  for (int k0 = 0; k0 < K; k0 += 32) {
    __syncthreads();  // prior iteration's LDS reads complete
    gll16(&Ahi[ga0 + k0], dA0);
    gll16(&Ahi[ga1 + k0], dA1);
    gll16(&Bh[gb0 + k0], dB0);
    gll16(&Bh[gb1 + k0], dB1);
    __syncthreads();  // vmcnt drained -> staging visible

    short8 ah[4], bh[4];
#pragma unroll
    for (int f = 0; f < 4; f++) {
      const int ra = wr * 64 + f * 16 + lar;
      const int ia = ra * 32 + ((lkf ^ ((ra >> 1) & 3)) << 3);
      ah[f] = *(const short8*)&sAh[ia];
      const int rb = wc * 64 + f * 16 + lar;
      const int ib = rb * 32 + ((lkf ^ ((rb >> 1) & 3)) << 3);
      bh[f] = *(const short8*)&sBh[ib];
    }
#pragma unroll
    for (int i = 0; i < 4; i++)
#pragma unroll
      for (int j = 0; j < 4; j++)
        acc[i][j] = __builtin_amdgcn_mfma_f32_16x16x32_bf16(ah[i], bh[j],
                                                            acc[i][j], 0, 0, 0);
  }

#pragma unroll
  for (int i = 0; i < 4; i++)
#pragma unroll
    for (int j = 0; j < 4; j++) {
      const int row = m0 + wr * 64 + i * 16 + (l >> 4) * 4;
      const int col = n0 + wc * 64 + j * 16 + (l & 15);
      const f32x4 v = acc[i][j];
#pragma unroll
      for (int q = 0; q < 4; q++)
        Cz[(size_t)(row + q) * N + col] = bhi(v[q]);
    }
}

// ---------------------------------------------------------------------------
// Per-row transform, one (row, mi) per block; input m is bf16. Emits
// q/k/(lam*v) as bf16 HI ONLY + per-head stats (q2/k2 fp32).
// ---------------------------------------------------------------------------
__global__ __launch_bounds__(768) void k_qkvt3(
    const float* __restrict__ xn2a,
    const unsigned short* __restrict__ mq, const unsigned short* __restrict__ mk,
    const unsigned short* __restrict__ mv,
    unsigned short* __restrict__ qhh, unsigned short* __restrict__ khh,
    unsigned short* __restrict__ vhh,
    float* __restrict__ q2n, float* __restrict__ k2n,
    float* __restrict__ lam1, float beta_ratio) {
  const int t = threadIdx.x;
  const int row = blockIdx.x;  // b*L + l
  const int mi = blockIdx.y;
  const int b = row >> 10, l = row & 1023;
  const int w = t >> 6, lane = t & 63;
  __shared__ float red[12];

  const unsigned short* m = (mi == 0) ? mq : (mi == 1) ? mk : mv;
  const float me = bf2f(m[(size_t)row * Dd + t]);
  const float s2 = wred64(me * me);
  if (lane == 0) red[w] = s2;
  __syncthreads();
  float mn2 = 0.0f;
#pragma unroll
  for (int i = 0; i < 12; i++) mn2 += red[i];

  const float xn = sqrtf(fmaxf(xn2a[row], EPSf * EPSf));
  const float arx = artanh_(fminf(xn, MAXN));

  const float mxn = sqrtf(fmaxf(mn2, EPSf * EPSf));
  const float pn = tanhf(mxn / xn * arx);
  const float c1 = pn / mxn * fminf(1.0f, MAXN / fmaxf(pn, EPSf));
  const float nn = fmaxf(fminf(pn, MAXN), EPSf);
  const float c2 = artanh_(nn) / nn;
  const float ve = c2 * c1 * me * beta_ratio;
  const float hs = wred64(ve * ve);
  const float hn = sqrtf(fmaxf(hs, EPSf * EPSf));
  const float th = tanhf(hn);
  const float oe = th / hn * ve;
  const size_t hidx = (size_t)(b * Hh + w) * Ll + l;
  const size_t oidx = hidx * DHh + lane;
  if (mi == 0) {
    qhh[oidx] = bhi(oe);
    if (lane == 0) q2n[hidx] = th * th;
  } else if (mi == 1) {
    khh[oidx] = bhi(oe);
    if (lane == 0) k2n[hidx] = th * th;
  } else {
    const float lam = 2.0f / fmaxf(1.0f - th * th, EPSf);
    vhh[oidx] = bhi(lam * oe);
    if (lane == 0) lam1[hidx] = lam - 1.0f;
  }
}

// ---------------------------------------------------------------------------
// Transpose lam*v per head: [k][d] -> [d][k] (bf16 hi only).
// ---------------------------------------------------------------------------
__global__ __launch_bounds__(256) void k_vt(const unsigned short* __restrict__ vh,
                                            unsigned short* __restrict__ th) {
  __shared__ __align__(16) unsigned short sh[64 * 72];
  const int t = threadIdx.x;
  const int bh = blockIdx.y, c = blockIdx.x;
  const size_t ibase = ((size_t)bh * Ll + c * 64) * DHh;
#pragma unroll
  for (int u = 0; u < 2; u++) {
    const int ch = t + u * 256, r = ch >> 3, f = ch & 7;
    *(short8*)&sh[r * 72 + f * 8] = *(const short8*)&vh[ibase + r * DHh + f * 8];
  }
  __syncthreads();
#pragma unroll
  for (int u = 0; u < 2; u++) {
    const int ch = t + u * 256, d = ch >> 3, kb = ch & 7;
    short8 oh;
#pragma unroll
    for (int i = 0; i < 8; i++) oh[i] = (short)sh[(kb * 8 + i) * 72 + d];
    const size_t ob = ((size_t)bh * DHh + d) * Ll + c * 64 + kb * 8;
    *(short8*)&th[ob] = oh;
  }
}

// ---------------------------------------------------------------------------
// Fused attention, SINGLE pass, double-buffered LDS, XCD-chunked swizzle.
// Q/K/V all bf16 hi-only: QK^T is ONE MFMA per (j,s); score via 1-t^2
// identity (perfect square -> robust). PV V hi. bf16(e) -> attn row first
// half; k_norm expands+normalizes.
// ---------------------------------------------------------------------------
__global__ __launch_bounds__(256) void k_attn1(
    const unsigned short* __restrict__ qhh, const unsigned short* __restrict__ khh,
    const unsigned short* __restrict__ vth,
    const float* __restrict__ q2n, const float* __restrict__ k2n,
    const float* __restrict__ lam1, const float* __restrict__ scale_p,
    float* __restrict__ attn, float* __restrict__ rowsum,
    float* __restrict__ yh) {
  __shared__ __align__(16) unsigned short kldsh[2][32 * 72];
  __shared__ __align__(16) unsigned short vldsh[2][64 * 36];
  __shared__ __align__(16) unsigned short wlds[4][16 * 36];
  __shared__ __align__(16) float k2s[2][32];
  __shared__ __align__(16) float l1s[2][32];
  __shared__ __align__(16) float ik2s[2][32];
  __shared__ float dred[4][16];
  const int t = threadIdx.x, l = t & 63, w = t >> 6;
  const int lr = l & 15, lg = l >> 4;
  // XCD swizzle: 1536 wgs, 192 per XCD; work/16 = head, work%16 = q-tile.
  const int lin = blockIdx.y * 16 + blockIdx.x;
  const int work = (lin & 7) * 192 + (lin >> 3);
  const int bh = work >> 4, q0 = (work & 15) * 64;
  const size_t hbase = (size_t)bh * Ll;
  const float scale = scale_p[0];
  const bool sone = (scale == 1.0f);

  short8 aqh[2];
#pragma unroll
  for (int s = 0; s < 2; s++) {
    const size_t off = (hbase + q0 + w * 16 + lr) * (size_t)DHh + s * 32 + lg * 8;
    aqh[s] = *(const short8*)&qhh[off];
  }
  const float q2v = q2n[hbase + q0 + w * 16 + lr];

  const int kr = t >> 3, kf = t & 7;
  const int vd = t >> 2, vf = t & 3;

  float rs = 0.0f, dacc = 0.0f;
  f32x4 pv[4] = {};

  short8 pkh, pvh;
  float k2r = 0.0f, l1r = 0.0f;
  auto load_chunk = [&](int c) {
    const size_t kg = (hbase + c * 32 + kr) * (size_t)DHh + kf * 8;
    pkh = *(const short8*)&khh[kg];
    const size_t vg = ((size_t)bh * DHh + vd) * (size_t)Ll + c * 32 + vf * 8;
    pvh = *(const short8*)&vth[vg];
    if (t < 32) {
      k2r = k2n[hbase + c * 32 + t];
      l1r = lam1[hbase + c * 32 + t];
    }
  };
  load_chunk(0);

  for (int c = 0; c < 32; c++) {
    const int pb = c & 1;
    *(short8*)&kldsh[pb][kr * 72 + kf * 8] = pkh;
    *(short8*)&vldsh[pb][vd * 36 + vf * 8] = pvh;
    if (t < 32) {
      k2s[pb][t] = k2r;
      l1s[pb][t] = l1r;
      ik2s[pb][t] = __builtin_amdgcn_rcpf(1.0f - k2r);
    }
    if (c + 1 < 32) load_chunk(c + 1);  // prefetch c+1 (regs only)
    __syncthreads();  // writes visible; prior reads of buf pb (c-2) done

#pragma unroll
    for (int j = 0; j < 2; j++) {
      f32x4 acc = {};
#pragma unroll
      for (int s = 0; s < 2; s++) {
        const int ko = (j * 16 + lr) * 72 + s * 32 + lg * 8;
        const short8 kfh = *(const short8*)&kldsh[pb][ko];
        acc = __builtin_amdgcn_mfma_f32_16x16x32_bf16(kfh, aqh[s], acc, 0, 0, 0);
      }
      const float4 k2q = *(const float4*)&k2s[pb][j * 16 + lg * 4];
      const float4 l1q = *(const float4*)&l1s[pb][j * 16 + lg * 4];
      const float4 ikq = *(const float4*)&ik2s[pb][j * 16 + lg * 4];
      const float kq[4] = {k2q.x, k2q.y, k2q.z, k2q.w};
      const float lq[4] = {l1q.x, l1q.y, l1q.z, l1q.w};
      const float iq[4] = {ikq.x, ikq.y, ikq.z, ikq.w};
      short4v wv;
#pragma unroll
      for (int r = 0; r < 4; r++) {
        const float qk2 = acc[r] + acc[r];
        const float d = fmaxf(q2v + kq[r] - qk2, 0.0f);
        const float dn = fmaf(q2v, kq[r], 1.0f) - qk2;  // > 0.4 here
        const float m_ = fmaxf(d * dn, 1e-30f);
        const float s_ = m_ * __builtin_amdgcn_rsqf(m_);  // sqrt(d*dn)
        float e = (dn + d - s_ - s_) * iq[r];  // (sqrt(dn)-sqrt(d))^2 >= 0
        if (!sone) e = expf(scale * logf(fmaxf(e, 1e-30f)));
        rs += e;
        __hip_bfloat16 eb = __float2bfloat16(e);
        wv[r] = *(short*)&eb;
        dacc += bf2f(*(unsigned short*)&eb) * lq[r];  // den from rounded w
      }
      *(short4v*)&wlds[w][lr * 36 + j * 16 + lg * 4] = wv;
    }
    // PV: A = w (16q x 32k, bf16, wave-local), B = (lam v)^T hi [d][k].
    {
      const short8 wa = *(const short8*)&wlds[w][lr * 36 + lg * 8];
#pragma unroll
      for (int n = 0; n < 4; n++) {
        const short8 vbh8 = *(const short8*)&vldsh[pb][(n * 16 + lr) * 36 + lg * 8];
        pv[n] = __builtin_amdgcn_mfma_f32_16x16x32_bf16(wa, vbh8, pv[n], 0, 0, 0);
      }
    }
    // Coalesced bf16-e store: wave-local re-read of wlds, 16B per lane.
    {
      const int qy = l >> 2, cg = l & 3;
      const short8 ev = *(const short8*)&wlds[w][qy * 36 + cg * 8];
      unsigned short* eb =
          (unsigned short*)(attn + (hbase + q0 + w * 16 + qy) * (size_t)Ll);
      *(short8*)&eb[c * 32 + cg * 8] = ev;
    }
  }

  rs += __shfl_xor(rs, 16, 64);
  rs += __shfl_xor(rs, 32, 64);
  if (lg == 0) rowsum[hbase + q0 + w * 16 + lr] = rs;

  dacc += __shfl_xor(dacc, 16, 64);
  dacc += __shfl_xor(dacc, 32, 64);
  if (lg == 0) dred[w][lr] = dacc;

  const int b = bh / Hh, h = bh % Hh;
#pragma unroll
  for (int r = 0; r < 4; r++) {
    float den = dred[w][lg * 4 + r];
    if (fabsf(den) < 1e-10f) den = 1e-10f;
    const float dinv = 1.0f / den;
    float tm[4];
    float n2 = 0.0f;
#pragma unroll
    for (int n = 0; n < 4; n++) {
      tm[n] = pv[n][r] * dinv;
      n2 += tm[n] * tm[n];
    }
    n2 += __shfl_xor(n2, 1, 64);
    n2 += __shfl_xor(n2, 2, 64);
    n2 += __shfl_xor(n2, 4, 64);
    n2 += __shfl_xor(n2, 8, 64);
    const float nn = sqrtf(fmaxf(n2, EPSf * EPSf));
    const float nc = fminf(nn, MAXN);
    const float pn = nc / (1.0f + sqrtf(fmaxf(1.0f - nc * nc, 0.0f)));
    const float f = pn / nn * fminf(1.0f, MAXN / fmaxf(pn, EPSf));
    const int ql = q0 + w * 16 + lg * 4 + r;
#pragma unroll
    for (int n = 0; n < 4; n++)
      yh[(((size_t)(b * Ll + ql)) * Hh + h) * DHh + n * 16 + lr] = f * tm[n];
  }
}

// ---------------------------------------------------------------------------
// Normalize + expand: one row per block. Row's bf16 e values occupy the
// first 2 KB of the 4 KB fp32 row; read all (registers), sync, write fp32.
// ---------------------------------------------------------------------------
__global__ __launch_bounds__(256) void k_norm(float* __restrict__ attn,
                                              const float* __restrict__ rowsum) {
  const int row = blockIdx.x;
  const float rinv = 1.0f / rowsum[row];
  float* prow = attn + (size_t)row * Ll;
  const ushort4 u4 = ((const ushort4*)prow)[threadIdx.x];  // 4 bf16 e
  __syncthreads();  // all reads done before in-place expansion writes
  float4 v;
  v.x = bf2f(u4.x) * rinv;
  v.y = bf2f(u4.y) * rinv;
  v.z = bf2f(u4.z) * rinv;
  v.w = bf2f(u4.w) * rinv;
  ((float4*)prow)[threadIdx.x] = v;
}

// ---------------------------------------------------------------------------
// beta_concat: per-head logmap0 / BETA_RATIO, then expmap0 over full D.
// Also emits the bf16 (hi-only) copy of yc for the projection GEMM.
// ---------------------------------------------------------------------------
__global__ __launch_bounds__(768) void k_concat(
    const float* __restrict__ yh, float* __restrict__ yc,
    unsigned short* __restrict__ ychi, float beta_ratio) {
  const int t = threadIdx.x;
  const int row = blockIdx.x;
  const int w = t >> 6, lane = t & 63;
  __shared__ float red[12];
  const float ye = yh[(size_t)row * Dd + t];
  const float hs = wred64(ye * ye);
  const float hn = sqrtf(fmaxf(hs, EPSf * EPSf));
  const float cc = artanh_(fminf(hn, MAXN)) / hn / beta_ratio;
  const float ve = cc * ye;
  const float s = wred64(ve * ve);
  if (lane == 0) red[w] = s;
  __syncthreads();
  float n2 = 0.0f;
#pragma unroll
  for (int i = 0; i < 12; i++) n2 += red[i];
  const float n = sqrtf(fmaxf(n2, EPSf * EPSf));
  const float f = tanhf(n) / n;
  const float o = f * ve;
  yc[(size_t)row * Dd + t] = o;
  ychi[(size_t)row * Dd + t] = bhi(o);
}

// ---------------------------------------------------------------------------
// Final: mobius_matvec scaling (project), mobius_add with bias, project.
// mp comes in as bf16.
// ---------------------------------------------------------------------------
__global__ __launch_bounds__(768) void k_final(
    const float* __restrict__ yc, const unsigned short* __restrict__ mp,
    const float* __restrict__ bp, float* __restrict__ out) {
  const int t = threadIdx.x;
  const int row = blockIdx.x;
  const int w = t >> 6, lane = t & 63;
  __shared__ float red[12];
  auto blockSum = [&](float v) -> float {
    __syncthreads();
    const float s = wred64(v);
    if (lane == 0) red[w] = s;
    __syncthreads();
    float tot = 0.0f;
#pragma unroll
    for (int i = 0; i < 12; i++) tot += red[i];
    return tot;
  };
  const float xe = yc[(size_t)row * Dd + t];
  const float me = bf2f(mp[(size_t)row * Dd + t]);
  const float be = bp[t];
  const float xn2 = blockSum(xe * xe);
  const float xn = sqrtf(fmaxf(xn2, EPSf * EPSf));
  const float arx = artanh_(fminf(xn, MAXN));
  const float mn2 = blockSum(me * me);
  const float mxn = sqrtf(fmaxf(mn2, EPSf * EPSf));
  const float pn = tanhf(mxn / xn * arx);
  const float c1 = pn / mxn * fminf(1.0f, MAXN / fmaxf(pn, EPSf));
  const float mme = c1 * me;
  const float x2 = blockSum(mme * mme);
  const float y2 = blockSum(be * be);
  const float xy = blockSum(mme * be);
  const float nume = (1.0f + 2.0f * xy + y2) * mme + (1.0f - x2) * be;
  const float den = fmaxf(1.0f + 2.0f * xy + x2 * y2, EPSf);
  const float re = nume / den;
  const float rn2 = blockSum(re * re);
  const float rn = sqrtf(fmaxf(rn2, EPSf * EPSf));
  const float f = fminf(1.0f, MAXN / rn);
  out[(size_t)row * Dd + t] = f * re;
}

}  // namespace

extern "C" void kernel_launch(void* const* d_in, const int* in_sizes, int n_in,
                              void* d_out, int out_size, void* d_ws,
                              size_t ws_size, hipStream_t stream) {
  const float* x = (const float*)d_in[0];
  const float* Wq = (const float*)d_in[1];
  const float* Wk = (const float*)d_in[2];
  const float* Wv = (const float*)d_in[3];
  const float* Wp = (const float*)d_in[4];
  const float* bp = (const float*)d_in[5];
  const float* scale = (const float*)d_in[6];

  float* out = (float*)d_out;
  float* y_out = out;                        // (B,L,D)
  float* attn = out + (size_t)Bb * Ll * Dd;  // (B,H,L,L)

  const size_t NH = (size_t)Bb * Hh * Ll;  // 98304
  const size_t RD = (size_t)Bb * Ll * Dd;  // 6291456

  unsigned short* u = (unsigned short*)d_ws;
  unsigned short* qhh = u;               // RD (dead after k_attn1)
  unsigned short* khh = u + RD;          // RD (dead after k_attn1)
  unsigned short* vth = u + 2 * RD;      // RD (dead after k_attn1)
  unsigned short* vhh = u + 3 * RD;      // RD (dead after k_vt)
  float* yh = (float*)(u + 4 * RD);      // RD floats (2 RD shorts)
  unsigned short* whi = u + 6 * RD;      // 4*DDm shorts
  float* fb = (float*)(whi + 4 * (size_t)DDm);
  float* q2n = fb;
  float* k2n = fb + NH;
  float* lam1 = fb + 2 * NH;
  float* rowsum = fb + 3 * NH;
  float* xn2a = fb + 4 * NH;  // 8192 floats
  // overlays for the tail (dead-region reuse):
  float* yc = (float*)u;              // RD floats over qhh/khh (post-attn1)
  unsigned short* ychi = u + 2 * RD;  // RD shorts over vth (post-attn1)
  unsigned short* mp = u + 4 * RD;    // RD shorts over yh (post-k_concat)

  // GEMM bf16 outputs + bf16 x staged in the not-yet-written attn region.
  unsigned short* mq = (unsigned short*)attn;
  unsigned short* mk = mq + RD;
  unsigned short* mv = mq + 2 * RD;
  unsigned short* xhi = mq + 3 * RD;

  const double br =
      exp(lgamma(DHh / 2.0) + lgamma(0.5) - lgamma(DHh / 2.0 + 0.5) -
          (lgamma(Dd / 2.0) + lgamma(0.5) - lgamma(Dd / 2.0 + 0.5)));
  const float beta_ratio = (float)br;

  (void)in_sizes; (void)n_in; (void)out_size; (void)ws_size;

  k_cvtx<<<dim3(Bb * Ll), dim3(768), 0, stream>>>(x, xhi, xn2a);
  k_cvt4<<<dim3(DDm / 4 / 256, 1, 4), dim3(256), 0, stream>>>(Wq, Wk, Wv, Wp,
                                                              whi);

  k_gemm_bf16h<<<dim3(Dd / 128, (Bb * Ll) / 128, 3), dim3(256), 0, stream>>>(
      xhi, whi, mq);

  k_qkvt3<<<dim3(Bb * Ll, 3), dim3(768), 0, stream>>>(
      xn2a, mq, mk, mv, qhh, khh, vhh, q2n, k2n, lam1, beta_ratio);

  k_vt<<<dim3(16, Bb * Hh), dim3(256), 0, stream>>>(vhh, vth);

  k_attn1<<<dim3(16, Bb * Hh), dim3(256), 0, stream>>>(
      qhh, khh, vth, q2n, k2n, lam1, scale, attn, rowsum, yh);

  k_norm<<<dim3((int)NH), dim3(256), 0, stream>>>(attn, rowsum);

  k_concat<<<dim3(Bb * Ll), dim3(768), 0, stream>>>(yh, yc, ychi, beta_ratio);

  k_gemm_bf16h<<<dim3(Dd / 128, (Bb * Ll) / 128, 1), dim3(256), 0, stream>>>(
      ychi, whi + 3 * (size_t)DDm, mp);

  k_final<<<dim3(Bb * Ll), dim3(768), 0, stream>>>(yc, mp, bp, y_out);
}